// Round 1
// baseline (3525.254 us; speedup 1.0000x reference)
//
#include <hip/hip_runtime.h>
#include <math.h>

#define BATCH 8
#define CH    192
#define WW    56
#define NPTS  3136
#define C2    384
#define CG    96

__device__ __forceinline__ float gelu_exact(float v) {
  return 0.5f * v * (1.0f + erff(v * 0.7071067811865475f));
}

// ---------------- K0: fold BN into weights, build cos-table ----------------
// regions: w1 36864 | b1 192 | wg 36864 | bg 384 | w2 73728 | b2 192 | ftab 56
__global__ void prep_kernel(
    const float* __restrict__ fc1_w, const float* __restrict__ fc1_b,
    const float* __restrict__ bn1_g, const float* __restrict__ bn1_b,
    const float* __restrict__ bn1_m, const float* __restrict__ bn1_v,
    const float* __restrict__ gc_w,  const float* __restrict__ gc_b,
    const float* __restrict__ bng_g, const float* __restrict__ bng_b,
    const float* __restrict__ bng_m, const float* __restrict__ bng_v,
    const float* __restrict__ fc2_w, const float* __restrict__ fc2_b,
    const float* __restrict__ bn2_g, const float* __restrict__ bn2_b,
    const float* __restrict__ bn2_m, const float* __restrict__ bn2_v,
    float* __restrict__ w1, float* __restrict__ b1,
    float* __restrict__ wg, float* __restrict__ bg,
    float* __restrict__ w2, float* __restrict__ b2,
    float* __restrict__ ftab)
{
  int i = blockIdx.x * 256 + threadIdx.x;
  if (i < 36864) {
    int d = i / CH;
    float s = bn1_g[d] / sqrtf(bn1_v[d] + 1e-5f);
    w1[i] = fc1_w[i] * s;
  } else if (i < 37056) {
    int d = i - 36864;
    float s = bn1_g[d] / sqrtf(bn1_v[d] + 1e-5f);
    b1[d] = (fc1_b[d] - bn1_m[d]) * s + bn1_b[d];
  } else if (i < 73920) {
    int j = i - 37056;
    int o = j / CG;   // layout [4][96][96] -> j/96 == g*96+dd
    float s = bng_g[o] / sqrtf(bng_v[o] + 1e-5f);
    wg[j] = gc_w[j] * s;
  } else if (i < 74304) {
    int o = i - 73920;
    float s = bng_g[o] / sqrtf(bng_v[o] + 1e-5f);
    bg[o] = (gc_b[o] - bng_m[o]) * s + bng_b[o];
  } else if (i < 148032) {
    int j = i - 74304;
    int d = j / C2;
    float s = bn2_g[d] / sqrtf(bn2_v[d] + 1e-5f);
    w2[j] = fc2_w[j] * s;
  } else if (i < 148224) {
    int d = i - 148032;
    float s = bn2_g[d] / sqrtf(bn2_v[d] + 1e-5f);
    b2[d] = (fc2_b[d] - bn2_m[d]) * s + bn2_b[d];
  } else if (i < 148280) {
    int delta = i - 148224;
    float s = 0.f;
    for (int t = 0; t < 48; ++t) {
      float omega = powf(10000.f, -(float)t / 48.f);
      s += cosf((float)delta * omega);
    }
    ftab[delta] = s;   // f(|dy|); rel = -2/C*(f(|dy|)+f(|dx|))
  }
}

// ---------------- K1: h = BN1(fc1(x^T)) ; h layout [b][n][c] ----------------
__global__ __launch_bounds__(256) void fc1_kernel(
    const float* __restrict__ x, const float* __restrict__ w1,
    const float* __restrict__ b1, float* __restrict__ h)
{
  __shared__ float As[64*68];
  __shared__ float Bs[64*68];
  const int tid = threadIdx.x;
  const int ntile = blockIdx.x, dt = blockIdx.y, b = blockIdx.z;
  const int n0 = ntile * 64, d0 = dt * 64;
  const int ty = tid >> 4, tx = tid & 15;
  const float* xb = x + (size_t)b * CH * NPTS;
  float acc[4][4] = {};
  for (int k0 = 0; k0 < CH; k0 += 64) {
    if (k0) __syncthreads();
#pragma unroll
    for (int p = 0; p < 16; ++p) {                 // As[r][kk] = x[b][k0+kk][n0+r]
      int e = p * 256 + tid;
      int kk = e >> 6, r = e & 63;
      As[r*68 + kk] = xb[(size_t)(k0 + kk) * NPTS + n0 + r];
    }
#pragma unroll
    for (int p = 0; p < 4; ++p) {                  // Bs[dd][kk] = w1[d0+dd][k0+kk]
      int e = p * 256 + tid;
      int dd = e >> 4, k4 = (e & 15) << 2;
      *(float4*)&Bs[dd*68 + k4] = *(const float4*)&w1[(size_t)(d0 + dd) * CH + k0 + k4];
    }
    __syncthreads();
#pragma unroll
    for (int kq = 0; kq < 16; ++kq) {
      float4 av[4], bv[4];
#pragma unroll
      for (int i = 0; i < 4; ++i) av[i] = *(const float4*)&As[(ty*4+i)*68 + kq*4];
#pragma unroll
      for (int j = 0; j < 4; ++j) bv[j] = *(const float4*)&Bs[(tx*4+j)*68 + kq*4];
#pragma unroll
      for (int i = 0; i < 4; ++i)
#pragma unroll
        for (int j = 0; j < 4; ++j)
          acc[i][j] += av[i].x*bv[j].x + av[i].y*bv[j].y + av[i].z*bv[j].z + av[i].w*bv[j].w;
    }
  }
#pragma unroll
  for (int i = 0; i < 4; ++i) {
    int n = n0 + ty*4 + i;
    float4 v;
    v.x = acc[i][0] + b1[d0 + tx*4 + 0];
    v.y = acc[i][1] + b1[d0 + tx*4 + 1];
    v.z = acc[i][2] + b1[d0 + tx*4 + 2];
    v.w = acc[i][3] + b1[d0 + tx*4 + 3];
    *(float4*)&h[((size_t)b * NPTS + n) * CH + d0 + tx*4] = v;
  }
}

// ---------------- K2: per-row inv-norm and sq = sum(xn^2) ----------------
__global__ __launch_bounds__(256) void norm_kernel(
    const float* __restrict__ h, float* __restrict__ invn, float* __restrict__ sqv)
{
  const int lane = threadIdx.x & 63;
  const int row = blockIdx.x * 4 + (threadIdx.x >> 6);
  const float* hr = h + (size_t)row * CH;
  float v0 = hr[lane], v1 = hr[lane + 64], v2 = hr[lane + 128];
  float s = v0*v0 + v1*v1 + v2*v2;
#pragma unroll
  for (int o = 32; o > 0; o >>= 1) s += __shfl_down(s, o);
  if (lane == 0) {
    float norm = sqrtf(s);
    float inv = 1.0f / fmaxf(norm, 1e-12f);
    invn[row] = inv;
    sqv[row] = s * inv * inv;
  }
}

// ---------------- K3: dist tile + running top-9 per row ----------------
// grid (49, 8) = (ntile, b); 256 threads; 64 n-rows per block, stream m in 64-tiles.
__global__ __launch_bounds__(256) void topk_kernel(
    const float* __restrict__ h, const float* __restrict__ invn,
    const float* __restrict__ sqv, const float* __restrict__ ftab_g,
    int* __restrict__ nn)
{
  __shared__ float S[2 * 64 * 68];      // As | Bs ; reused as merge buffer
  __shared__ float Ds[64][67];
  __shared__ float ft[56];
  __shared__ float invA[64], invB[64], sqB[64];
  float* As = S;
  float* Bs = S + 64 * 68;

  const int tid = threadIdx.x;
  const int ntile = blockIdx.x, b = blockIdx.y;
  const int n0 = ntile * 64;
  const int ty = tid >> 4, tx = tid & 15;
  const int r_s = tid >> 2, q_s = tid & 3;
  const float* hb = h + (size_t)b * NPTS * CH;
  const int rowbase = b * NPTS;

  if (tid < 64) invA[tid] = invn[rowbase + n0 + tid];
  if (tid < 56) ft[tid] = ftab_g[tid];

  float ld[9]; int li[9];
#pragma unroll
  for (int k = 0; k < 9; ++k) { ld[k] = INFINITY; li[k] = 0x7fffffff; }

  for (int mt = 0; mt < 49; ++mt) {
    const int m0 = mt * 64;
    float acc[4][4] = {};
    __syncthreads();                                    // prior scan / As,Bs use done
    if (tid < 64) { invB[tid] = invn[rowbase + m0 + tid]; sqB[tid] = sqv[rowbase + m0 + tid]; }
    __syncthreads();
    for (int k0 = 0; k0 < CH; k0 += 64) {
      if (k0) __syncthreads();
#pragma unroll
      for (int p = 0; p < 16; ++p) {
        int e = p * 256 + tid;
        int r = e & 63, kk = e >> 6;
        As[r*68 + kk] = hb[(size_t)(n0 + r) * CH + k0 + kk] * invA[r];
      }
#pragma unroll
      for (int p = 0; p < 16; ++p) {
        int e = p * 256 + tid;
        int r = e & 63, kk = e >> 6;
        Bs[r*68 + kk] = hb[(size_t)(m0 + r) * CH + k0 + kk] * invB[r];
      }
      __syncthreads();
#pragma unroll
      for (int kq = 0; kq < 16; ++kq) {
        float4 av[4], bv[4];
#pragma unroll
        for (int i = 0; i < 4; ++i) av[i] = *(const float4*)&As[(ty*4+i)*68 + kq*4];
#pragma unroll
        for (int j = 0; j < 4; ++j) bv[j] = *(const float4*)&Bs[(tx*4+j)*68 + kq*4];
#pragma unroll
        for (int i = 0; i < 4; ++i)
#pragma unroll
          for (int j = 0; j < 4; ++j)
            acc[i][j] += av[i].x*bv[j].x + av[i].y*bv[j].y + av[i].z*bv[j].z + av[i].w*bv[j].w;
      }
    }
    // dist tile (sq_n dropped: row-constant, can't change ranking or ties)
#pragma unroll
    for (int i = 0; i < 4; ++i) {
      int n = n0 + ty*4 + i;
      int yn = n / WW, xn_ = n % WW;
#pragma unroll
      for (int j = 0; j < 4; ++j) {
        int m = m0 + tx*4 + j;
        int ym = m / WW, xm_ = m % WW;
        int dy = yn - ym; dy = dy < 0 ? -dy : dy;
        int dx = xn_ - xm_; dx = dx < 0 ? -dx : dx;
        float rel = -(2.0f / (float)CH) * (ft[dy] + ft[dx]);
        Ds[ty*4 + i][tx*4 + j] = sqB[tx*4 + j] - 2.0f * acc[i][j] + rel;
      }
    }
    __syncthreads();
    // scan: thread (r_s, q_s) owns 16 m-columns of its row; m increases in-thread
#pragma unroll
    for (int j = 0; j < 16; ++j) {
      float d = Ds[r_s][q_s*16 + j];
      if (d < ld[8]) {
        float cd = d; int ci = m0 + q_s*16 + j;
#pragma unroll
        for (int s = 0; s < 9; ++s) {
          if (cd < ld[s]) { float t0 = ld[s]; int t1 = li[s]; ld[s] = cd; li[s] = ci; cd = t0; ci = t1; }
        }
      }
    }
  }
  __syncthreads();
  // merge 4 sorted lists per row (lex (dist, idx) like lax.top_k tie-breaking)
  float* Msd = S;
  int*   Msi = (int*)(S + 64 * 4 * 9);
#pragma unroll
  for (int k = 0; k < 9; ++k) {          // r_s*4+q_s == tid
    Msd[tid * 9 + k] = ld[k];
    Msi[tid * 9 + k] = li[k];
  }
  __syncthreads();
  if (tid < 64) {
    const int lbase = tid * 4;
    int p0 = 0, p1 = 0, p2 = 0, p3 = 0;
    int* nrow = nn + (size_t)(rowbase + n0 + tid) * 9;
    for (int k = 0; k < 9; ++k) {
      float bd = (p0 < 9) ? Msd[(lbase+0)*9 + p0] : INFINITY;
      int   bi = (p0 < 9) ? Msi[(lbase+0)*9 + p0] : 0x7fffffff;
      int   bq = 0;
      float d1 = (p1 < 9) ? Msd[(lbase+1)*9 + p1] : INFINITY;
      int   i1 = (p1 < 9) ? Msi[(lbase+1)*9 + p1] : 0x7fffffff;
      if (d1 < bd || (d1 == bd && i1 < bi)) { bd = d1; bi = i1; bq = 1; }
      float d2 = (p2 < 9) ? Msd[(lbase+2)*9 + p2] : INFINITY;
      int   i2 = (p2 < 9) ? Msi[(lbase+2)*9 + p2] : 0x7fffffff;
      if (d2 < bd || (d2 == bd && i2 < bi)) { bd = d2; bi = i2; bq = 2; }
      float d3 = (p3 < 9) ? Msd[(lbase+3)*9 + p3] : INFINITY;
      int   i3 = (p3 < 9) ? Msi[(lbase+3)*9 + p3] : 0x7fffffff;
      if (d3 < bd || (d3 == bd && i3 < bi)) { bd = d3; bi = i3; bq = 3; }
      if (bq == 0) ++p0; else if (bq == 1) ++p1; else if (bq == 2) ++p2; else ++p3;
      nrow[k] = bi;
    }
  }
}

// ---------------- K4: gather+max (groups 2,3) + grouped GEMM + GELU ----------------
// grid (392, 8) = (64-row tile, 48-wide output col tile); y layout [row][384]
__global__ __launch_bounds__(256) void gc_kernel(
    const float* __restrict__ h, const int* __restrict__ nn,
    const float* __restrict__ wg, const float* __restrict__ bg,
    float* __restrict__ y)
{
  __shared__ float Gs[64][52];
  __shared__ float Ws[48][52];
  __shared__ int nns[576];
  const int tid = threadIdx.x;
  const int rt = blockIdx.x, ct = blockIdx.y;
  const int n0g = rt * 64;
  const int b = n0g / NPTS;
  const int rowbase = b * NPTS;
  const int g = ct >> 1;
  const int dd0 = ct * 48;              // global output column (row of wg'[384][96])
  const bool isD = (g >= 2);
  const int cin0 = (g & 1) * CG;        // h-column base for this group
  if (isD) {
    for (int e = tid; e < 576; e += 256)
      nns[e] = nn[(size_t)(n0g + e / 9) * 9 + (e % 9)];
  }
  const int ty = tid >> 4, tx = tid & 15;
  float acc[4][3] = {};
  for (int k0 = 0; k0 < CG; k0 += 48) {
    __syncthreads();
    for (int e = tid; e < 3072; e += 256) {
      int r = e / 48, kk = e % 48;
      int c = cin0 + k0 + kk;
      const float* hc = h + c;
      float hv = hc[(size_t)(n0g + r) * CH];
      float v;
      if (isD) {
        float mx = -INFINITY;
#pragma unroll
        for (int k = 0; k < 9; ++k)
          mx = fmaxf(mx, hc[(size_t)(rowbase + nns[r*9 + k]) * CH]);
        v = mx - hv;
      } else v = hv;
      Gs[r][kk] = v;
    }
    for (int e = tid; e < 2304; e += 256) {
      int dd = e / 48, kk = e % 48;
      Ws[dd][kk] = wg[(size_t)(dd0 + dd) * CG + k0 + kk];
    }
    __syncthreads();
#pragma unroll
    for (int kq = 0; kq < 12; ++kq) {
      float4 av[4], bv[3];
#pragma unroll
      for (int i = 0; i < 4; ++i) av[i] = *(const float4*)&Gs[ty*4 + i][kq*4];
#pragma unroll
      for (int j = 0; j < 3; ++j) bv[j] = *(const float4*)&Ws[tx*3 + j][kq*4];
#pragma unroll
      for (int i = 0; i < 4; ++i)
#pragma unroll
        for (int j = 0; j < 3; ++j)
          acc[i][j] += av[i].x*bv[j].x + av[i].y*bv[j].y + av[i].z*bv[j].z + av[i].w*bv[j].w;
    }
  }
#pragma unroll
  for (int i = 0; i < 4; ++i) {
    int row = n0g + ty*4 + i;
#pragma unroll
    for (int j = 0; j < 3; ++j) {
      int oc = dd0 + tx*3 + j;
      float v = acc[i][j] + bg[oc];
      y[(size_t)row * C2 + oc] = gelu_exact(v);
    }
  }
}

// ---------------- K5: fc2 + BN2 + residual, transposed coalesced store ----------------
__global__ __launch_bounds__(256) void fc2_kernel(
    const float* __restrict__ yv, const float* __restrict__ w2, const float* __restrict__ b2,
    const float* __restrict__ x, float* __restrict__ out)
{
  __shared__ float As[64*68];
  __shared__ float Bs[64*68];
  __shared__ float Os[64*68];
  const int tid = threadIdx.x;
  const int rt = blockIdx.x, dt = blockIdx.y;
  const int n0g = rt * 64;
  const int b = n0g / NPTS;
  const int nloc0 = n0g - b * NPTS;
  const int d0 = dt * 64;
  const int ty = tid >> 4, tx = tid & 15;
  float acc[4][4] = {};
  for (int k0 = 0; k0 < C2; k0 += 64) {
    if (k0) __syncthreads();
#pragma unroll
    for (int p = 0; p < 4; ++p) {
      int e = p * 256 + tid;
      int r = e >> 4, k4 = (e & 15) << 2;
      *(float4*)&As[r*68 + k4] = *(const float4*)&yv[(size_t)(n0g + r) * C2 + k0 + k4];
    }
#pragma unroll
    for (int p = 0; p < 4; ++p) {
      int e = p * 256 + tid;
      int dd = e >> 4, k4 = (e & 15) << 2;
      *(float4*)&Bs[dd*68 + k4] = *(const float4*)&w2[(size_t)(d0 + dd) * C2 + k0 + k4];
    }
    __syncthreads();
#pragma unroll
    for (int kq = 0; kq < 16; ++kq) {
      float4 av[4], bv[4];
#pragma unroll
      for (int i = 0; i < 4; ++i) av[i] = *(const float4*)&As[(ty*4+i)*68 + kq*4];
#pragma unroll
      for (int j = 0; j < 4; ++j) bv[j] = *(const float4*)&Bs[(tx*4+j)*68 + kq*4];
#pragma unroll
      for (int i = 0; i < 4; ++i)
#pragma unroll
        for (int j = 0; j < 4; ++j)
          acc[i][j] += av[i].x*bv[j].x + av[i].y*bv[j].y + av[i].z*bv[j].z + av[i].w*bv[j].w;
    }
  }
  __syncthreads();
#pragma unroll
  for (int i = 0; i < 4; ++i)
#pragma unroll
    for (int j = 0; j < 4; ++j)
      Os[(tx*4 + j)*68 + ty*4 + i] = acc[i][j];   // transpose to [c][n]
  __syncthreads();
#pragma unroll
  for (int p = 0; p < 4; ++p) {
    int cl = (tid >> 4) + p * 16;
    int n4 = (tid & 15) << 2;
    float4 v = *(const float4*)&Os[cl*68 + n4];
    size_t gi = ((size_t)b * CH + d0 + cl) * NPTS + nloc0 + n4;
    float bb = b2[d0 + cl];
    float4 xr = *(const float4*)&x[gi];
    v.x += bb + xr.x; v.y += bb + xr.y; v.z += bb + xr.z; v.w += bb + xr.w;
    *(float4*)&out[gi] = v;
  }
}

extern "C" void kernel_launch(void* const* d_in, const int* in_sizes, int n_in,
                              void* d_out, int out_size, void* d_ws, size_t ws_size,
                              hipStream_t stream) {
  const float* x     = (const float*)d_in[0];
  const float* fc1_w = (const float*)d_in[1];
  const float* fc1_b = (const float*)d_in[2];
  const float* bn1_g = (const float*)d_in[3];
  const float* bn1_b = (const float*)d_in[4];
  const float* bn1_m = (const float*)d_in[5];
  const float* bn1_v = (const float*)d_in[6];
  const float* gc_w  = (const float*)d_in[7];
  const float* gc_b  = (const float*)d_in[8];
  const float* bng_g = (const float*)d_in[9];
  const float* bng_b = (const float*)d_in[10];
  const float* bng_m = (const float*)d_in[11];
  const float* bng_v = (const float*)d_in[12];
  const float* fc2_w = (const float*)d_in[13];
  const float* fc2_b = (const float*)d_in[14];
  const float* bn2_g = (const float*)d_in[15];
  const float* bn2_b = (const float*)d_in[16];
  const float* bn2_m = (const float*)d_in[17];
  const float* bn2_v = (const float*)d_in[18];

  float* ws = (float*)d_ws;
  size_t o = 0;
  float* W1 = ws + o; o += 36864;
  float* B1 = ws + o; o += 192;
  float* WG = ws + o; o += 36864;
  float* BG = ws + o; o += 384;
  float* W2 = ws + o; o += 73728;
  float* B2 = ws + o; o += 192;
  float* FT = ws + o; o += 64;
  float* H  = ws + o; o += (size_t)25088 * 192;
  float* INV= ws + o; o += 25088;
  float* SQ = ws + o; o += 25088;
  int*   NN = (int*)(ws + o); o += 25088 * 9;
  float* Y  = ws + o; o += (size_t)25088 * 384;
  (void)ws_size; (void)in_sizes; (void)n_in; (void)out_size;

  hipLaunchKernelGGL(prep_kernel, dim3(580), dim3(256), 0, stream,
                     fc1_w, fc1_b, bn1_g, bn1_b, bn1_m, bn1_v,
                     gc_w, gc_b, bng_g, bng_b, bng_m, bng_v,
                     fc2_w, fc2_b, bn2_g, bn2_b, bn2_m, bn2_v,
                     W1, B1, WG, BG, W2, B2, FT);
  hipLaunchKernelGGL(fc1_kernel, dim3(49, 3, 8), dim3(256), 0, stream, x, W1, B1, H);
  hipLaunchKernelGGL(norm_kernel, dim3(6272), dim3(256), 0, stream, H, INV, SQ);
  hipLaunchKernelGGL(topk_kernel, dim3(49, 8), dim3(256), 0, stream, H, INV, SQ, FT, NN);
  hipLaunchKernelGGL(gc_kernel, dim3(392, 8), dim3(256), 0, stream, H, NN, WG, BG, Y);
  hipLaunchKernelGGL(fc2_kernel, dim3(392, 3), dim3(256), 0, stream, Y, W2, B2, x, (float*)d_out);
}

// Round 3
// 1632.399 us; speedup vs baseline: 2.1596x; 2.1596x over previous
//
#include <hip/hip_runtime.h>
#include <math.h>

#define BATCH 8
#define CH    192
#define WW    56
#define NPTS  3136
#define C2    384
#define CG    96
#define MSPLIT 4
#define BN    128
#define MT    32
#define LK    12
#define NCAND (MSPLIT*LK)
#define NREF  16

typedef float f32x4 __attribute__((ext_vector_type(4)));
typedef short bf16x8 __attribute__((ext_vector_type(8)));

__device__ __forceinline__ float gelu_exact(float v) {
  return 0.5f * v * (1.0f + erff(v * 0.7071067811865475f));
}
__device__ __forceinline__ unsigned short f2bf(float f) {
  unsigned int u = __float_as_uint(f);
  u = u + 0x7fffu + ((u >> 16) & 1u);
  return (unsigned short)(u >> 16);
}
__device__ __forceinline__ float bf2f(unsigned short h) {
  return __uint_as_float(((unsigned int)h) << 16);
}

// ---------------- K0: fold BN into weights, build cos-table ----------------
__global__ void prep_kernel(
    const float* __restrict__ fc1_w, const float* __restrict__ fc1_b,
    const float* __restrict__ bn1_g, const float* __restrict__ bn1_b,
    const float* __restrict__ bn1_m, const float* __restrict__ bn1_v,
    const float* __restrict__ gc_w,  const float* __restrict__ gc_b,
    const float* __restrict__ bng_g, const float* __restrict__ bng_b,
    const float* __restrict__ bng_m, const float* __restrict__ bng_v,
    const float* __restrict__ fc2_w, const float* __restrict__ fc2_b,
    const float* __restrict__ bn2_g, const float* __restrict__ bn2_b,
    const float* __restrict__ bn2_m, const float* __restrict__ bn2_v,
    float* __restrict__ w1, float* __restrict__ b1,
    float* __restrict__ wg, float* __restrict__ bg,
    float* __restrict__ w2, float* __restrict__ b2,
    float* __restrict__ ftab)
{
  int i = blockIdx.x * 256 + threadIdx.x;
  if (i < 36864) {
    int d = i / CH;
    float s = bn1_g[d] / sqrtf(bn1_v[d] + 1e-5f);
    w1[i] = fc1_w[i] * s;
  } else if (i < 37056) {
    int d = i - 36864;
    float s = bn1_g[d] / sqrtf(bn1_v[d] + 1e-5f);
    b1[d] = (fc1_b[d] - bn1_m[d]) * s + bn1_b[d];
  } else if (i < 73920) {
    int j = i - 37056;
    int o = j / CG;
    float s = bng_g[o] / sqrtf(bng_v[o] + 1e-5f);
    wg[j] = gc_w[j] * s;
  } else if (i < 74304) {
    int o = i - 73920;
    float s = bng_g[o] / sqrtf(bng_v[o] + 1e-5f);
    bg[o] = (gc_b[o] - bng_m[o]) * s + bng_b[o];
  } else if (i < 148032) {
    int j = i - 74304;
    int d = j / C2;
    float s = bn2_g[d] / sqrtf(bn2_v[d] + 1e-5f);
    w2[j] = fc2_w[j] * s;
  } else if (i < 148224) {
    int d = i - 148032;
    float s = bn2_g[d] / sqrtf(bn2_v[d] + 1e-5f);
    b2[d] = (fc2_b[d] - bn2_m[d]) * s + bn2_b[d];
  } else if (i < 148280) {
    int delta = i - 148224;
    float s = 0.f;
    for (int t = 0; t < 48; ++t) {
      float omega = powf(10000.f, -(float)t / 48.f);
      s += cosf((float)delta * omega);
    }
    ftab[delta] = s;
  }
}

// ---------------- K1: h = BN1(fc1(x^T)) ; h layout [b][n][c] ----------------
__global__ __launch_bounds__(256) void fc1_kernel(
    const float* __restrict__ x, const float* __restrict__ w1,
    const float* __restrict__ b1, float* __restrict__ h)
{
  __shared__ float As[64*68];
  __shared__ float Bs[64*68];
  const int tid = threadIdx.x;
  const int ntile = blockIdx.x, dt = blockIdx.y, b = blockIdx.z;
  const int n0 = ntile * 64, d0 = dt * 64;
  const int ty = tid >> 4, tx = tid & 15;
  const float* xb = x + (size_t)b * CH * NPTS;
  float acc[4][4] = {};
  for (int k0 = 0; k0 < CH; k0 += 64) {
    if (k0) __syncthreads();
#pragma unroll
    for (int p = 0; p < 16; ++p) {
      int e = p * 256 + tid;
      int kk = e >> 6, r = e & 63;
      As[r*68 + kk] = xb[(size_t)(k0 + kk) * NPTS + n0 + r];
    }
#pragma unroll
    for (int p = 0; p < 4; ++p) {
      int e = p * 256 + tid;
      int dd = e >> 4, k4 = (e & 15) << 2;
      *(float4*)&Bs[dd*68 + k4] = *(const float4*)&w1[(size_t)(d0 + dd) * CH + k0 + k4];
    }
    __syncthreads();
#pragma unroll
    for (int kq = 0; kq < 16; ++kq) {
      float4 av[4], bv[4];
#pragma unroll
      for (int i = 0; i < 4; ++i) av[i] = *(const float4*)&As[(ty*4+i)*68 + kq*4];
#pragma unroll
      for (int j = 0; j < 4; ++j) bv[j] = *(const float4*)&Bs[(tx*4+j)*68 + kq*4];
#pragma unroll
      for (int i = 0; i < 4; ++i)
#pragma unroll
        for (int j = 0; j < 4; ++j)
          acc[i][j] += av[i].x*bv[j].x + av[i].y*bv[j].y + av[i].z*bv[j].z + av[i].w*bv[j].w;
    }
  }
#pragma unroll
  for (int i = 0; i < 4; ++i) {
    int n = n0 + ty*4 + i;
    float4 v;
    v.x = acc[i][0] + b1[d0 + tx*4 + 0];
    v.y = acc[i][1] + b1[d0 + tx*4 + 1];
    v.z = acc[i][2] + b1[d0 + tx*4 + 2];
    v.w = acc[i][3] + b1[d0 + tx*4 + 3];
    *(float4*)&h[((size_t)b * NPTS + n) * CH + d0 + tx*4] = v;
  }
}

// ---------------- K2: xn (f32 + bf16 hi/lo split) + sq ----------------
__global__ __launch_bounds__(256) void norm_kernel(
    const float* __restrict__ h, float* __restrict__ xnf,
    unsigned short* __restrict__ xhi, unsigned short* __restrict__ xlo,
    float* __restrict__ sqv)
{
  const int lane = threadIdx.x & 63;
  const int row = blockIdx.x * 4 + (threadIdx.x >> 6);
  const float* hr = h + (size_t)row * CH;
  float v0 = hr[lane], v1 = hr[lane + 64], v2 = hr[lane + 128];
  float s = v0*v0 + v1*v1 + v2*v2;
#pragma unroll
  for (int o = 32; o > 0; o >>= 1) s += __shfl_xor(s, o);
  float inv = 1.0f / fmaxf(sqrtf(s), 1e-12f);
  float x0 = v0 * inv, x1 = v1 * inv, x2 = v2 * inv;
  size_t base = (size_t)row * CH;
  xnf[base + lane      ] = x0;
  xnf[base + lane + 64 ] = x1;
  xnf[base + lane + 128] = x2;
  unsigned short h0 = f2bf(x0), h1 = f2bf(x1), h2 = f2bf(x2);
  xhi[base + lane      ] = h0;
  xhi[base + lane + 64 ] = h1;
  xhi[base + lane + 128] = h2;
  xlo[base + lane      ] = f2bf(x0 - bf2f(h0));
  xlo[base + lane + 64 ] = f2bf(x1 - bf2f(h1));
  xlo[base + lane + 128] = f2bf(x2 - bf2f(h2));
  if (lane == 0) sqv[row] = s * inv * inv;
}

// ---------------- K3: MFMA coarse dist + running top-12 per m-quarter ----------------
#define SCAN_TILE(MBASE) do {                                                      \
  _Pragma("unroll")                                                               \
  for (int j = 0; j < 16; ++j) {                                                  \
    float d_ = Ds[sr][sqc + j];                                                   \
    if (d_ < ld[LK-1]) {                                                          \
      float cd = d_; int ci = (MBASE) + sqc + j;                                  \
      _Pragma("unroll")                                                           \
      for (int s = 0; s < LK; ++s) {                                              \
        if (cd < ld[s]) { float t0=ld[s]; int t1=li[s]; ld[s]=cd; li[s]=ci; cd=t0; ci=t1; } \
      }                                                                           \
    }                                                                             \
  }                                                                               \
} while (0)

__global__ __launch_bounds__(256) void topk_kernel(
    const unsigned short* __restrict__ xhi, const unsigned short* __restrict__ xlo,
    const float* __restrict__ sqv, const float* __restrict__ ftab_g,
    float* __restrict__ pd, int* __restrict__ pi)
{
  __shared__ __align__(16) unsigned short Bh[MT * 192];   // XOR-swizzled rows, pitch 384B
  __shared__ __align__(16) unsigned short Bl[MT * 192];
  __shared__ float Ds[BN][MT + 1];
  __shared__ float ft[56];
  __shared__ float sqs[MT];

  const int tid  = threadIdx.x;
  const int lane = tid & 63;
  const int w    = tid >> 6;
  const int nt = blockIdx.x, ms = blockIdx.y, b = blockIdx.z;
  const int n0 = nt * BN;
  const size_t rowbase = (size_t)b * NPTS;

  if (tid < 56) ft[tid] = ftab_g[tid];

  const int ar = lane & 15;
  const int ak = (lane >> 4) * 8;

  bf16x8 ahi[2][6], alo[2][6];
#pragma unroll
  for (int rt = 0; rt < 2; ++rt) {
    int an = n0 + w * 32 + rt * 16 + ar;
    if (an > NPTS - 1) an = NPTS - 1;
    const unsigned short* ph = xhi + (rowbase + an) * CH + ak;
    const unsigned short* pl = xlo + (rowbase + an) * CH + ak;
#pragma unroll
    for (int c = 0; c < 6; ++c) {
      ahi[rt][c] = *(const bf16x8*)(ph + c * 32);
      alo[rt][c] = *(const bf16x8*)(pl + c * 32);
    }
  }

  int yn[2][4], xn_[2][4];
#pragma unroll
  for (int rt = 0; rt < 2; ++rt)
#pragma unroll
    for (int i = 0; i < 4; ++i) {
      int n = n0 + w * 32 + rt * 16 + (lane >> 4) * 4 + i;
      if (n > NPTS - 1) n = NPTS - 1;
      yn[rt][i] = n / WW; xn_[rt][i] = n % WW;
    }

  const int t0   = ms * 24 + (ms < 2 ? ms : 2);
  const int tcnt = 25 - (ms >= 2 ? 1 : 0);

  float ld[LK]; int li[LK];
#pragma unroll
  for (int k = 0; k < LK; ++k) { ld[k] = INFINITY; li[k] = 0x7fffffff; }

  const int sr  = tid >> 1;
  const int sqc = (tid & 1) * 16;

  int srow[3], skoff[3];
#pragma unroll
  for (int i = 0; i < 3; ++i) {
    int q = tid + 256 * i;
    srow[i] = q / 24;
    skoff[i] = (q % 24);
  }

  uint4 rh[3], rl[3];
  {
    const int m0 = t0 * MT;
#pragma unroll
    for (int i = 0; i < 3; ++i) {
      rh[i] = *(const uint4*)(xhi + (rowbase + m0 + srow[i]) * CH + skoff[i] * 8);
      rl[i] = *(const uint4*)(xlo + (rowbase + m0 + srow[i]) * CH + skoff[i] * 8);
    }
  }

  for (int tt = 0; tt < tcnt; ++tt) {
    const int m0 = (t0 + tt) * MT;
#pragma unroll
    for (int i = 0; i < 3; ++i) {
      int bb = srow[i] * 384 + ((skoff[i] * 16) ^ ((srow[i] & 7) << 4));
      *(uint4*)((char*)Bh + bb) = rh[i];
      *(uint4*)((char*)Bl + bb) = rl[i];
    }
    if (tid < MT) sqs[tid] = sqv[rowbase + m0 + tid];
    if (tt > 0) { const int mp = m0 - MT; SCAN_TILE(mp); }
    __syncthreads();
    if (tt + 1 < tcnt) {
      const int m1 = m0 + MT;
#pragma unroll
      for (int i = 0; i < 3; ++i) {
        rh[i] = *(const uint4*)(xhi + (rowbase + m1 + srow[i]) * CH + skoff[i] * 8);
        rl[i] = *(const uint4*)(xlo + (rowbase + m1 + srow[i]) * CH + skoff[i] * 8);
      }
    }
    f32x4 acc[2][2] = {};
#pragma unroll
    for (int ct = 0; ct < 2; ++ct) {
#pragma unroll
      for (int c = 0; c < 6; ++c) {
        int rB = ct * 16 + ar;
        int off = rB * 384 + ((c * 64 + (lane >> 4) * 16) ^ ((rB & 7) << 4));
        bf16x8 bh = *(const bf16x8*)((const char*)Bh + off);
        bf16x8 bl = *(const bf16x8*)((const char*)Bl + off);
#pragma unroll
        for (int rt = 0; rt < 2; ++rt) {
          acc[rt][ct] = __builtin_amdgcn_mfma_f32_16x16x32_bf16(ahi[rt][c], bh, acc[rt][ct], 0, 0, 0);
          acc[rt][ct] = __builtin_amdgcn_mfma_f32_16x16x32_bf16(alo[rt][c], bh, acc[rt][ct], 0, 0, 0);
          acc[rt][ct] = __builtin_amdgcn_mfma_f32_16x16x32_bf16(ahi[rt][c], bl, acc[rt][ct], 0, 0, 0);
        }
      }
    }
#pragma unroll
    for (int rt = 0; rt < 2; ++rt)
#pragma unroll
      for (int ct = 0; ct < 2; ++ct)
#pragma unroll
        for (int i = 0; i < 4; ++i) {
          int rowd = w * 32 + rt * 16 + (lane >> 4) * 4 + i;
          int col  = ct * 16 + ar;
          int m = m0 + col;
          int ym = m / WW, xm = m % WW;
          int dy = yn[rt][i] - ym; dy = dy < 0 ? -dy : dy;
          int dx = xn_[rt][i] - xm; dx = dx < 0 ? -dx : dx;
          float rel = -(2.0f / (float)CH) * (ft[dy] + ft[dx]);
          Ds[rowd][col] = sqs[col] - 2.0f * acc[rt][ct][i] + rel;
        }
    __syncthreads();
  }
  { const int mlast = (t0 + tcnt - 1) * MT; SCAN_TILE(mlast); }

  __syncthreads();
  float* Md = (float*)Bh;   // 256*12*4 = 12288B == sizeof(Bh)
  int*   Mi = (int*)Bl;
#pragma unroll
  for (int k = 0; k < LK; ++k) { Md[tid * LK + k] = ld[k]; Mi[tid * LK + k] = li[k]; }
  __syncthreads();
  if (tid < BN) {
    int n = n0 + tid;
    if (n < NPTS) {
      const int l0 = (tid * 2) * LK, l1 = (tid * 2 + 1) * LK;
      int p0 = 0, p1 = 0;
      float* od = pd + ((rowbase + n) * MSPLIT + ms) * LK;
      int*   oi = pi + ((rowbase + n) * MSPLIT + ms) * LK;
      for (int k = 0; k < LK; ++k) {
        float d0 = Md[l0 + p0]; int i0 = Mi[l0 + p0];
        float d1 = Md[l1 + p1]; int i1 = Mi[l1 + p1];
        bool take1 = (d1 < d0) || (d1 == d0 && i1 < i0);
        if (take1) { od[k] = d1; oi[k] = i1; ++p1; }
        else       { od[k] = d0; oi[k] = i0; ++p0; }
      }
    }
  }
}

// ---------------- K3b: pool 48 coarse candidates -> exact f32 refine -> top-9 ----------------
__global__ __launch_bounds__(256) void refine_kernel(
    const float* __restrict__ pd, const int* __restrict__ pi,
    const float* __restrict__ xn, const float* __restrict__ sqv,
    const float* __restrict__ ftab_g, int* __restrict__ nn)
{
  __shared__ float alld[4][NCAND];
  __shared__ int   alli[4][NCAND];
  __shared__ int   ci_s[4][NREF];
  __shared__ float ft[56];
  const int tid = threadIdx.x;
  const int w = tid >> 6, lane = tid & 63;
  if (tid < 56) ft[tid] = ftab_g[tid];
  const int row = blockIdx.x * 4 + w;
  const int b = row / NPTS;
  const int n_loc = row - b * NPTS;

  if (lane < NCAND) {
    alld[w][lane] = pd[(size_t)row * NCAND + lane];
    alli[w][lane] = pi[(size_t)row * NCAND + lane];
  }
  __syncthreads();
  // rank-select coarse top-16 (ranks unique: indices all distinct)
  if (lane < NCAND) {
    float d0 = alld[w][lane]; int i0 = alli[w][lane];
    int rank = 0;
    for (int j = 0; j < NCAND; ++j) {
      float dj = alld[w][j]; int ij = alli[w][j];
      rank += (dj < d0 || (dj == d0 && ij < i0)) ? 1 : 0;
    }
    if (rank < NREF) ci_s[w][rank] = i0;
  }
  __syncthreads();

  const float* xrow = xn + (size_t)row * CH;
  float a0 = xrow[lane], a1 = xrow[lane + 64], a2 = xrow[lane + 128];
  const int yn_ = n_loc / WW, xq_ = n_loc % WW;
  const size_t xbase = (size_t)b * NPTS * CH;
  float myd = INFINITY; int myi = 0x7fffffff;
#pragma unroll 4
  for (int c = 0; c < NREF; ++c) {
    int m = ci_s[w][c];
    const float* xm = xn + xbase + (size_t)m * CH;
    float s = a0 * xm[lane] + a1 * xm[lane + 64] + a2 * xm[lane + 128];
#pragma unroll
    for (int o = 32; o > 0; o >>= 1) s += __shfl_xor(s, o);
    if (lane == c) {
      int ym = m / WW, xm_ = m % WW;
      int dy = yn_ - ym; dy = dy < 0 ? -dy : dy;
      int dx = xq_ - xm_; dx = dx < 0 ? -dx : dx;
      myd = sqv[(size_t)b * NPTS + m] - 2.0f * s - (2.0f / (float)CH) * (ft[dy] + ft[dx]);
      myi = m;
    }
  }
  if (lane < NREF) {
    int rank = 0;
    for (int j = 0; j < NREF; ++j) {
      float dj = __shfl(myd, j); int ij = __shfl(myi, j);
      rank += (dj < myd || (dj == myd && ij < myi)) ? 1 : 0;
    }
    if (rank < 9) nn[(size_t)row * 9 + rank] = myi;
  }
}

// ---------------- K4: gather+max + grouped GEMM + GELU ----------------
__global__ __launch_bounds__(256) void gc_kernel(
    const float* __restrict__ h, const int* __restrict__ nn,
    const float* __restrict__ wg, const float* __restrict__ bg,
    float* __restrict__ y)
{
  __shared__ float Gs[64][52];
  __shared__ float Ws[48][52];
  __shared__ int nns[576];
  const int tid = threadIdx.x;
  const int rt = blockIdx.x, ct = blockIdx.y;
  const int n0g = rt * 64;
  const int b = n0g / NPTS;
  const int rowbase = b * NPTS;
  const int g = ct >> 1;
  const int dd0 = ct * 48;
  const bool isD = (g >= 2);
  const int cin0 = (g & 1) * CG;
  if (isD) {
    for (int e = tid; e < 576; e += 256)
      nns[e] = nn[(size_t)(n0g + e / 9) * 9 + (e % 9)];
  }
  const int ty = tid >> 4, tx = tid & 15;
  float acc[4][3] = {};
  for (int k0 = 0; k0 < CG; k0 += 48) {
    __syncthreads();
    for (int e = tid; e < 3072; e += 256) {
      int r = e / 48, kk = e % 48;
      int c = cin0 + k0 + kk;
      const float* hc = h + c;
      float hv = hc[(size_t)(n0g + r) * CH];
      float v;
      if (isD) {
        float mx = -INFINITY;
#pragma unroll
        for (int k = 0; k < 9; ++k)
          mx = fmaxf(mx, hc[(size_t)(rowbase + nns[r*9 + k]) * CH]);
        v = mx - hv;
      } else v = hv;
      Gs[r][kk] = v;
    }
    for (int e = tid; e < 2304; e += 256) {
      int dd = e / 48, kk = e % 48;
      Ws[dd][kk] = wg[(size_t)(dd0 + dd) * CG + k0 + kk];
    }
    __syncthreads();
#pragma unroll
    for (int kq = 0; kq < 12; ++kq) {
      float4 av[4], bv[3];
#pragma unroll
      for (int i = 0; i < 4; ++i) av[i] = *(const float4*)&Gs[ty*4 + i][kq*4];
#pragma unroll
      for (int j = 0; j < 3; ++j) bv[j] = *(const float4*)&Ws[tx*3 + j][kq*4];
#pragma unroll
      for (int i = 0; i < 4; ++i)
#pragma unroll
        for (int j = 0; j < 3; ++j)
          acc[i][j] += av[i].x*bv[j].x + av[i].y*bv[j].y + av[i].z*bv[j].z + av[i].w*bv[j].w;
    }
  }
#pragma unroll
  for (int i = 0; i < 4; ++i) {
    int row = n0g + ty*4 + i;
#pragma unroll
    for (int j = 0; j < 3; ++j) {
      int oc = dd0 + tx*3 + j;
      float v = acc[i][j] + bg[oc];
      y[(size_t)row * C2 + oc] = gelu_exact(v);
    }
  }
}

// ---------------- K5: fc2 + BN2 + residual ----------------
__global__ __launch_bounds__(256) void fc2_kernel(
    const float* __restrict__ yv, const float* __restrict__ w2, const float* __restrict__ b2,
    const float* __restrict__ x, float* __restrict__ out)
{
  __shared__ float As[64*68];
  __shared__ float Bs[64*68];
  __shared__ float Os[64*68];
  const int tid = threadIdx.x;
  const int rt = blockIdx.x, dt = blockIdx.y;
  const int n0g = rt * 64;
  const int b = n0g / NPTS;
  const int nloc0 = n0g - b * NPTS;
  const int d0 = dt * 64;
  const int ty = tid >> 4, tx = tid & 15;
  float acc[4][4] = {};
  for (int k0 = 0; k0 < C2; k0 += 64) {
    if (k0) __syncthreads();
#pragma unroll
    for (int p = 0; p < 4; ++p) {
      int e = p * 256 + tid;
      int r = e >> 4, k4 = (e & 15) << 2;
      *(float4*)&As[r*68 + k4] = *(const float4*)&yv[(size_t)(n0g + r) * C2 + k0 + k4];
    }
#pragma unroll
    for (int p = 0; p < 4; ++p) {
      int e = p * 256 + tid;
      int dd = e >> 4, k4 = (e & 15) << 2;
      *(float4*)&Bs[dd*68 + k4] = *(const float4*)&w2[(size_t)(d0 + dd) * C2 + k0 + k4];
    }
    __syncthreads();
#pragma unroll
    for (int kq = 0; kq < 16; ++kq) {
      float4 av[4], bv[4];
#pragma unroll
      for (int i = 0; i < 4; ++i) av[i] = *(const float4*)&As[(ty*4+i)*68 + kq*4];
#pragma unroll
      for (int j = 0; j < 4; ++j) bv[j] = *(const float4*)&Bs[(tx*4+j)*68 + kq*4];
#pragma unroll
      for (int i = 0; i < 4; ++i)
#pragma unroll
        for (int j = 0; j < 4; ++j)
          acc[i][j] += av[i].x*bv[j].x + av[i].y*bv[j].y + av[i].z*bv[j].z + av[i].w*bv[j].w;
    }
  }
  __syncthreads();
#pragma unroll
  for (int i = 0; i < 4; ++i)
#pragma unroll
    for (int j = 0; j < 4; ++j)
      Os[(tx*4 + j)*68 + ty*4 + i] = acc[i][j];
  __syncthreads();
#pragma unroll
  for (int p = 0; p < 4; ++p) {
    int cl = (tid >> 4) + p * 16;
    int n4 = (tid & 15) << 2;
    float4 v = *(const float4*)&Os[cl*68 + n4];
    size_t gi = ((size_t)b * CH + d0 + cl) * NPTS + nloc0 + n4;
    float bb = b2[d0 + cl];
    float4 xr = *(const float4*)&x[gi];
    v.x += bb + xr.x; v.y += bb + xr.y; v.z += bb + xr.z; v.w += bb + xr.w;
    *(float4*)&out[gi] = v;
  }
}

extern "C" void kernel_launch(void* const* d_in, const int* in_sizes, int n_in,
                              void* d_out, int out_size, void* d_ws, size_t ws_size,
                              hipStream_t stream) {
  const float* x     = (const float*)d_in[0];
  const float* fc1_w = (const float*)d_in[1];
  const float* fc1_b = (const float*)d_in[2];
  const float* bn1_g = (const float*)d_in[3];
  const float* bn1_b = (const float*)d_in[4];
  const float* bn1_m = (const float*)d_in[5];
  const float* bn1_v = (const float*)d_in[6];
  const float* gc_w  = (const float*)d_in[7];
  const float* gc_b  = (const float*)d_in[8];
  const float* bng_g = (const float*)d_in[9];
  const float* bng_b = (const float*)d_in[10];
  const float* bng_m = (const float*)d_in[11];
  const float* bng_v = (const float*)d_in[12];
  const float* fc2_w = (const float*)d_in[13];
  const float* fc2_b = (const float*)d_in[14];
  const float* bn2_g = (const float*)d_in[15];
  const float* bn2_b = (const float*)d_in[16];
  const float* bn2_m = (const float*)d_in[17];
  const float* bn2_v = (const float*)d_in[18];

  float* ws = (float*)d_ws;
  size_t o = 0;
  float* W1 = ws + o; o += 36864;
  float* B1 = ws + o; o += 192;
  float* WG = ws + o; o += 36864;
  float* BG = ws + o; o += 384;
  float* W2 = ws + o; o += 73728;
  float* B2 = ws + o; o += 192;
  float* FT = ws + o; o += 64;
  float* H  = ws + o; o += (size_t)25088 * 192;     // 4,816,896 f32
  float* SQ = ws + o; o += 25088;
  int*   NN = (int*)(ws + o); o += 25088 * 9;       // 225,792
  float* SCR = ws + o;                               // scratch union
  unsigned short* XHI = (unsigned short*)SCR;                         // 2.4M f32-equiv
  unsigned short* XLO = XHI + (size_t)25088 * 192;                    // 2.4M f32-equiv
  float* XN  = SCR + (size_t)4816896;                                 // 4,816,896 f32
  float* PD  = XN + (size_t)4816896;                                  // 25088*48 f32
  int*   PI  = (int*)(PD + (size_t)25088 * NCAND);                    // 25088*48 int
  float* Y   = SCR;   // 9,633,792 f32; alive only after refine (XHI..PI dead)
  (void)ws_size; (void)in_sizes; (void)n_in; (void)out_size;

  hipLaunchKernelGGL(prep_kernel, dim3(580), dim3(256), 0, stream,
                     fc1_w, fc1_b, bn1_g, bn1_b, bn1_m, bn1_v,
                     gc_w, gc_b, bng_g, bng_b, bng_m, bng_v,
                     fc2_w, fc2_b, bn2_g, bn2_b, bn2_m, bn2_v,
                     W1, B1, WG, BG, W2, B2, FT);
  hipLaunchKernelGGL(fc1_kernel, dim3(49, 3, 8), dim3(256), 0, stream, x, W1, B1, H);
  hipLaunchKernelGGL(norm_kernel, dim3(6272), dim3(256), 0, stream, H, XN, XHI, XLO, SQ);
  hipLaunchKernelGGL(topk_kernel, dim3(25, MSPLIT, 8), dim3(256), 0, stream, XHI, XLO, SQ, FT, PD, PI);
  hipLaunchKernelGGL(refine_kernel, dim3(6272), dim3(256), 0, stream, PD, PI, XN, SQ, FT, NN);
  hipLaunchKernelGGL(gc_kernel, dim3(392, 8), dim3(256), 0, stream, H, NN, WG, BG, Y);
  hipLaunchKernelGGL(fc2_kernel, dim3(392, 3), dim3(256), 0, stream, Y, W2, B2, x, (float*)d_out);
}

// Round 4
// 1496.691 us; speedup vs baseline: 2.3554x; 1.0907x over previous
//
#include <hip/hip_runtime.h>
#include <math.h>

#define BATCH 8
#define CH    192
#define WW    56
#define NPTS  3136
#define C2    384
#define CG    96
#define MT    32
#define LK    12
#define NCAND 24
#define NREF  16

typedef float f32x4 __attribute__((ext_vector_type(4)));
typedef short bf16x8 __attribute__((ext_vector_type(8)));

__device__ __forceinline__ float gelu_exact(float v) {
  return 0.5f * v * (1.0f + erff(v * 0.7071067811865475f));
}
__device__ __forceinline__ unsigned short f2bf(float f) {
  unsigned int u = __float_as_uint(f);
  u = u + 0x7fffu + ((u >> 16) & 1u);
  return (unsigned short)(u >> 16);
}
__device__ __forceinline__ float bf2f(unsigned short h) {
  return __uint_as_float(((unsigned int)h) << 16);
}

// ---------------- K0: fold BN into weights, build scaled cos-table ----------------
__global__ void prep_kernel(
    const float* __restrict__ fc1_w, const float* __restrict__ fc1_b,
    const float* __restrict__ bn1_g, const float* __restrict__ bn1_b,
    const float* __restrict__ bn1_m, const float* __restrict__ bn1_v,
    const float* __restrict__ gc_w,  const float* __restrict__ gc_b,
    const float* __restrict__ bng_g, const float* __restrict__ bng_b,
    const float* __restrict__ bng_m, const float* __restrict__ bng_v,
    const float* __restrict__ fc2_w, const float* __restrict__ fc2_b,
    const float* __restrict__ bn2_g, const float* __restrict__ bn2_b,
    const float* __restrict__ bn2_m, const float* __restrict__ bn2_v,
    float* __restrict__ w1, float* __restrict__ b1,
    float* __restrict__ wg, float* __restrict__ bg,
    float* __restrict__ w2, float* __restrict__ b2,
    float* __restrict__ ftab)
{
  int i = blockIdx.x * 256 + threadIdx.x;
  if (i < 36864) {
    int d = i / CH;
    float s = bn1_g[d] / sqrtf(bn1_v[d] + 1e-5f);
    w1[i] = fc1_w[i] * s;
  } else if (i < 37056) {
    int d = i - 36864;
    float s = bn1_g[d] / sqrtf(bn1_v[d] + 1e-5f);
    b1[d] = (fc1_b[d] - bn1_m[d]) * s + bn1_b[d];
  } else if (i < 73920) {
    int j = i - 37056;
    int o = j / CG;
    float s = bng_g[o] / sqrtf(bng_v[o] + 1e-5f);
    wg[j] = gc_w[j] * s;
  } else if (i < 74304) {
    int o = i - 73920;
    float s = bng_g[o] / sqrtf(bng_v[o] + 1e-5f);
    bg[o] = (gc_b[o] - bng_m[o]) * s + bng_b[o];
  } else if (i < 148032) {
    int j = i - 74304;
    int d = j / C2;
    float s = bn2_g[d] / sqrtf(bn2_v[d] + 1e-5f);
    w2[j] = fc2_w[j] * s;
  } else if (i < 148224) {
    int d = i - 148032;
    float s = bn2_g[d] / sqrtf(bn2_v[d] + 1e-5f);
    b2[d] = (fc2_b[d] - bn2_m[d]) * s + bn2_b[d];
  } else if (i < 148280) {
    int delta = i - 148224;
    float s = 0.f;
    for (int t = 0; t < 48; ++t) {
      float omega = powf(10000.f, -(float)t / 48.f);
      s += cosf((float)delta * omega);
    }
    ftab[delta] = s * (-2.0f / (float)CH);   // pre-scaled: rel = ft[dy]+ft[dx]
  }
}

// ---------------- K1: h = BN1(fc1(x^T)) ; h layout [b][n][c] ----------------
__global__ __launch_bounds__(256) void fc1_kernel(
    const float* __restrict__ x, const float* __restrict__ w1,
    const float* __restrict__ b1, float* __restrict__ h)
{
  __shared__ float As[64*68];
  __shared__ float Bs[64*68];
  const int tid = threadIdx.x;
  const int ntile = blockIdx.x, dt = blockIdx.y, b = blockIdx.z;
  const int n0 = ntile * 64, d0 = dt * 64;
  const int ty = tid >> 4, tx = tid & 15;
  const float* xb = x + (size_t)b * CH * NPTS;
  float acc[4][4] = {};
  for (int k0 = 0; k0 < CH; k0 += 64) {
    if (k0) __syncthreads();
#pragma unroll
    for (int p = 0; p < 16; ++p) {
      int e = p * 256 + tid;
      int kk = e >> 6, r = e & 63;
      As[r*68 + kk] = xb[(size_t)(k0 + kk) * NPTS + n0 + r];
    }
#pragma unroll
    for (int p = 0; p < 4; ++p) {
      int e = p * 256 + tid;
      int dd = e >> 4, k4 = (e & 15) << 2;
      *(float4*)&Bs[dd*68 + k4] = *(const float4*)&w1[(size_t)(d0 + dd) * CH + k0 + k4];
    }
    __syncthreads();
#pragma unroll
    for (int kq = 0; kq < 16; ++kq) {
      float4 av[4], bv[4];
#pragma unroll
      for (int i = 0; i < 4; ++i) av[i] = *(const float4*)&As[(ty*4+i)*68 + kq*4];
#pragma unroll
      for (int j = 0; j < 4; ++j) bv[j] = *(const float4*)&Bs[(tx*4+j)*68 + kq*4];
#pragma unroll
      for (int i = 0; i < 4; ++i)
#pragma unroll
        for (int j = 0; j < 4; ++j)
          acc[i][j] += av[i].x*bv[j].x + av[i].y*bv[j].y + av[i].z*bv[j].z + av[i].w*bv[j].w;
    }
  }
#pragma unroll
  for (int i = 0; i < 4; ++i) {
    int n = n0 + ty*4 + i;
    float4 v;
    v.x = acc[i][0] + b1[d0 + tx*4 + 0];
    v.y = acc[i][1] + b1[d0 + tx*4 + 1];
    v.z = acc[i][2] + b1[d0 + tx*4 + 2];
    v.w = acc[i][3] + b1[d0 + tx*4 + 3];
    *(float4*)&h[((size_t)b * NPTS + n) * CH + d0 + tx*4] = v;
  }
}

// ---------------- K2: xn (f32 + bf16 hi/lo split) + sq ----------------
__global__ __launch_bounds__(256) void norm_kernel(
    const float* __restrict__ h, float* __restrict__ xnf,
    unsigned short* __restrict__ xhi, unsigned short* __restrict__ xlo,
    float* __restrict__ sqv)
{
  const int lane = threadIdx.x & 63;
  const int row = blockIdx.x * 4 + (threadIdx.x >> 6);
  const float* hr = h + (size_t)row * CH;
  float v0 = hr[lane], v1 = hr[lane + 64], v2 = hr[lane + 128];
  float s = v0*v0 + v1*v1 + v2*v2;
#pragma unroll
  for (int o = 32; o > 0; o >>= 1) s += __shfl_xor(s, o);
  float inv = 1.0f / fmaxf(sqrtf(s), 1e-12f);
  float x0 = v0 * inv, x1 = v1 * inv, x2 = v2 * inv;
  size_t base = (size_t)row * CH;
  xnf[base + lane      ] = x0;
  xnf[base + lane + 64 ] = x1;
  xnf[base + lane + 128] = x2;
  unsigned short h0 = f2bf(x0), h1 = f2bf(x1), h2 = f2bf(x2);
  xhi[base + lane      ] = h0;
  xhi[base + lane + 64 ] = h1;
  xhi[base + lane + 128] = h2;
  xlo[base + lane      ] = f2bf(x0 - bf2f(h0));
  xlo[base + lane + 64 ] = f2bf(x1 - bf2f(h1));
  xlo[base + lane + 128] = f2bf(x2 - bf2f(h2));
  if (lane == 0) sqv[row] = s * inv * inv;
}

// ---------------- K3: MFMA coarse dist, per-lane register top-12 ----------------
// grid (49, 2, 8); block 256 = 4 waves. Wave w owns 16 n (= n0+w*16+ar), lane's
// acc column is its FIXED n; m streams through LDS in 32-row tiles (hi/lo bf16).
__global__ __launch_bounds__(256, 2) void topk_kernel(
    const unsigned short* __restrict__ xhi, const unsigned short* __restrict__ xlo,
    const float* __restrict__ fts_g,
    float* __restrict__ pd, int* __restrict__ pi)
{
  __shared__ __align__(16) unsigned short Ah[MT * 192];   // 12288 B, XOR-swizzled rows
  __shared__ __align__(16) unsigned short Al[MT * 192];
  __shared__ float ft[56];

  const int tid  = threadIdx.x;
  const int lane = tid & 63;
  const int w    = tid >> 6;
  const int nt = blockIdx.x, ms = blockIdx.y, b = blockIdx.z;
  const int n0 = nt * 64;
  const size_t rowbase = (size_t)b * NPTS;

  if (tid < 56) ft[tid] = fts_g[tid];

  const int ar = lane & 15;
  const int hi = lane >> 4;
  const int ak = hi * 8;

  // B fragments (n-side) in registers
  const int n_b = n0 + w * 16 + ar;
  bf16x8 bhi[6], blo[6];
  {
    const unsigned short* pbh = xhi + (rowbase + n_b) * CH + ak;
    const unsigned short* pbl = xlo + (rowbase + n_b) * CH + ak;
#pragma unroll
    for (int c = 0; c < 6; ++c) {
      bhi[c] = *(const bf16x8*)(pbh + c * 32);
      blo[c] = *(const bf16x8*)(pbl + c * 32);
    }
  }
  const int yn_l = n_b / WW, xn_l = n_b % WW;

  float ld[LK]; int li[LK];
#pragma unroll
  for (int k = 0; k < LK; ++k) { ld[k] = INFINITY; li[k] = 0x7fffffff; }

  // staging: 768 16B chunks per buffer, 3 per thread
  int srow[3], skoff[3];
#pragma unroll
  for (int i = 0; i < 3; ++i) {
    int q = tid + 256 * i;
    srow[i] = q / 24;
    skoff[i] = q % 24;
  }

  const int mbase = ms * (NPTS / 2);     // 0 or 1568 = 28*56
  uint4 rh[3], rl[3];
#pragma unroll
  for (int i = 0; i < 3; ++i) {
    rh[i] = *(const uint4*)(xhi + (rowbase + mbase + srow[i]) * CH + skoff[i] * 8);
    rl[i] = *(const uint4*)(xlo + (rowbase + mbase + srow[i]) * CH + skoff[i] * 8);
  }

  int ym0 = ms * 28, xm0 = 0;            // coords of m0, updated incrementally

  for (int tt = 0; tt < 49; ++tt) {
    const int m0 = mbase + tt * MT;
    // phase A: write staged regs -> LDS (swizzled)
#pragma unroll
    for (int i = 0; i < 3; ++i) {
      int bb = srow[i] * 384 + ((skoff[i] * 16) ^ ((srow[i] & 7) << 4));
      *(uint4*)((char*)Ah + bb) = rh[i];
      *(uint4*)((char*)Al + bb) = rl[i];
    }
    __syncthreads();
    // phase B: prefetch next tile
    if (tt + 1 < 49) {
      const int m1 = m0 + MT;
#pragma unroll
      for (int i = 0; i < 3; ++i) {
        rh[i] = *(const uint4*)(xhi + (rowbase + m1 + srow[i]) * CH + skoff[i] * 8);
        rl[i] = *(const uint4*)(xlo + (rowbase + m1 + srow[i]) * CH + skoff[i] * 8);
      }
    }
    // MFMA: D[m(32) x n(16)] ; acc col = n (fixed per lane), rows = m
    f32x4 acc[2] = {};
#pragma unroll
    for (int rt = 0; rt < 2; ++rt) {
      const int rA = rt * 16 + ar;
      const int swz = (rA & 7) << 4;
#pragma unroll
      for (int c = 0; c < 6; ++c) {
        int off = rA * 384 + ((c * 64 + hi * 16) ^ swz);
        bf16x8 ah = *(const bf16x8*)((const char*)Ah + off);
        bf16x8 al = *(const bf16x8*)((const char*)Al + off);
        acc[rt] = __builtin_amdgcn_mfma_f32_16x16x32_bf16(ah, bhi[c], acc[rt], 0, 0, 0);
        acc[rt] = __builtin_amdgcn_mfma_f32_16x16x32_bf16(ah, blo[c], acc[rt], 0, 0, 0);
        acc[rt] = __builtin_amdgcn_mfma_f32_16x16x32_bf16(al, bhi[c], acc[rt], 0, 0, 0);
      }
    }
    // epilogue: 8 values per lane, m = m0 + rt*16 + hi*4 + i (ascending)
#pragma unroll
    for (int rt = 0; rt < 2; ++rt) {
#pragma unroll
      for (int i = 0; i < 4; ++i) {
        const int off_m = rt * 16 + hi * 4 + i;
        int xm = xm0 + off_m, ym = ym0;
        if (xm >= WW) { xm -= WW; ym += 1; }
        int dy = yn_l - ym; dy = dy < 0 ? -dy : dy;
        int dx = xn_l - xm; dx = dx < 0 ? -dx : dx;
        float d_ = ft[dy] + ft[dx] - 2.0f * acc[rt][i];
        if (d_ < ld[LK-1]) {
          float cd = d_; int ci = m0 + off_m;
#pragma unroll
          for (int s = 0; s < LK; ++s) {
            if (cd < ld[s]) { float t0=ld[s]; int t1=li[s]; ld[s]=cd; li[s]=ci; cd=t0; ci=t1; }
          }
        }
      }
    }
    xm0 += MT;
    if (xm0 >= WW) { xm0 -= WW; ym0 += 1; }
    __syncthreads();   // Ah/Al reads done before next overwrite
  }

  // tail: 4-way merge per n (hi-lanes 0..3), write top-12 per (n, ms)
  float* Md = (float*)Ah;   // 256*12*4 = 12288 B, exact fit
  int*   Mi = (int*)Al;
#pragma unroll
  for (int k = 0; k < LK; ++k) { Md[tid * LK + k] = ld[k]; Mi[tid * LK + k] = li[k]; }
  __syncthreads();
  if (tid < 64) {
    const int wv = tid >> 4, arr = tid & 15;
    const int n = n0 + tid;     // == n0 + wv*16 + arr
    int lb[4];
#pragma unroll
    for (int hq = 0; hq < 4; ++hq) lb[hq] = (wv * 64 + hq * 16 + arr) * LK;
    int p0 = 0, p1 = 0, p2 = 0, p3 = 0;
    float* od = pd + ((rowbase + n) * 2 + ms) * LK;
    int*   oi = pi + ((rowbase + n) * 2 + ms) * LK;
    for (int k = 0; k < LK; ++k) {
      float bd = Md[lb[0] + p0]; int bi = Mi[lb[0] + p0]; int bq = 0;
      float dv = Md[lb[1] + p1]; int iv = Mi[lb[1] + p1];
      if (dv < bd || (dv == bd && iv < bi)) { bd = dv; bi = iv; bq = 1; }
      dv = Md[lb[2] + p2]; iv = Mi[lb[2] + p2];
      if (dv < bd || (dv == bd && iv < bi)) { bd = dv; bi = iv; bq = 2; }
      dv = Md[lb[3] + p3]; iv = Mi[lb[3] + p3];
      if (dv < bd || (dv == bd && iv < bi)) { bd = dv; bi = iv; bq = 3; }
      if (bq == 0) { if (p0 < LK-1) ++p0; else Md[lb[0]+p0] = INFINITY; }
      else if (bq == 1) { if (p1 < LK-1) ++p1; else Md[lb[1]+p1] = INFINITY; }
      else if (bq == 2) { if (p2 < LK-1) ++p2; else Md[lb[2]+p2] = INFINITY; }
      else              { if (p3 < LK-1) ++p3; else Md[lb[3]+p3] = INFINITY; }
      od[k] = bd; oi[k] = bi;
    }
  }
}

// ---------------- K3b: pool 24 coarse candidates -> exact f32 refine -> top-9 ----------------
__global__ __launch_bounds__(256) void refine_kernel(
    const float* __restrict__ pd, const int* __restrict__ pi,
    const float* __restrict__ xn, const float* __restrict__ sqv,
    const float* __restrict__ fts_g, int* __restrict__ nn)
{
  __shared__ float alld[4][NCAND];
  __shared__ int   alli[4][NCAND];
  __shared__ int   ci_s[4][NREF];
  __shared__ float ft[56];
  const int tid = threadIdx.x;
  const int w = tid >> 6, lane = tid & 63;
  if (tid < 56) ft[tid] = fts_g[tid];
  const int row = blockIdx.x * 4 + w;
  const int b = row / NPTS;
  const int n_loc = row - b * NPTS;

  if (lane < NCAND) {
    alld[w][lane] = pd[(size_t)row * NCAND + lane];
    alli[w][lane] = pi[(size_t)row * NCAND + lane];
  }
  __syncthreads();
  if (lane < NCAND) {
    float d0 = alld[w][lane]; int i0 = alli[w][lane];
    int rank = 0;
    for (int j = 0; j < NCAND; ++j) {
      float dj = alld[w][j]; int ij = alli[w][j];
      rank += (dj < d0 || (dj == d0 && ij < i0)) ? 1 : 0;
    }
    if (rank < NREF) ci_s[w][rank] = i0;
  }
  __syncthreads();

  const float* xrow = xn + (size_t)row * CH;
  float a0 = xrow[lane], a1 = xrow[lane + 64], a2 = xrow[lane + 128];
  const int yn_ = n_loc / WW, xq_ = n_loc % WW;
  const size_t xbase = (size_t)b * NPTS * CH;
  float myd = INFINITY; int myi = 0x7fffffff;
#pragma unroll 4
  for (int c = 0; c < NREF; ++c) {
    int m = ci_s[w][c];
    const float* xm = xn + xbase + (size_t)m * CH;
    float s = a0 * xm[lane] + a1 * xm[lane + 64] + a2 * xm[lane + 128];
#pragma unroll
    for (int o = 32; o > 0; o >>= 1) s += __shfl_xor(s, o);
    if (lane == c) {
      int ym = m / WW, xm_ = m % WW;
      int dy = yn_ - ym; dy = dy < 0 ? -dy : dy;
      int dx = xq_ - xm_; dx = dx < 0 ? -dx : dx;
      myd = sqv[(size_t)b * NPTS + m] - 2.0f * s + (ft[dy] + ft[dx]);
      myi = m;
    }
  }
  if (lane < NREF) {
    int rank = 0;
    for (int j = 0; j < NREF; ++j) {
      float dj = __shfl(myd, j); int ij = __shfl(myi, j);
      rank += (dj < myd || (dj == myd && ij < myi)) ? 1 : 0;
    }
    if (rank < 9) nn[(size_t)row * 9 + rank] = myi;
  }
}

// ---------------- K3c: edge features d = max_j(x_j) - h, once ----------------
__global__ __launch_bounds__(256) void edge_kernel(
    const float* __restrict__ h, const int* __restrict__ nn,
    float* __restrict__ df)
{
  __shared__ int nns[576];
  const int n0g = blockIdx.x * 64;
  const int b = n0g / NPTS;
  const size_t rowbase = (size_t)b * NPTS;
  const int tid = threadIdx.x;
  for (int e = tid; e < 576; e += 256)
    nns[e] = nn[(size_t)(n0g + e / 9) * 9 + (e % 9)];
  __syncthreads();
#pragma unroll
  for (int p = 0; p < 12; ++p) {
    int e = tid + 256 * p;
    int r = e / 48, c4 = (e % 48) * 4;
    float4 hv = *(const float4*)&h[(size_t)(n0g + r) * CH + c4];
    float4 mx = make_float4(-INFINITY, -INFINITY, -INFINITY, -INFINITY);
#pragma unroll
    for (int k = 0; k < 9; ++k) {
      float4 nv = *(const float4*)&h[(rowbase + nns[r*9 + k]) * CH + c4];
      mx.x = fmaxf(mx.x, nv.x); mx.y = fmaxf(mx.y, nv.y);
      mx.z = fmaxf(mx.z, nv.z); mx.w = fmaxf(mx.w, nv.w);
    }
    float4 ov;
    ov.x = mx.x - hv.x; ov.y = mx.y - hv.y; ov.z = mx.z - hv.z; ov.w = mx.w - hv.w;
    *(float4*)&df[(size_t)(n0g + r) * CH + c4] = ov;
  }
}

// ---------------- K4: grouped GEMM + GELU (no gathers), y in bf16 ----------------
__global__ __launch_bounds__(256) void gc_kernel(
    const float* __restrict__ h, const float* __restrict__ df,
    const float* __restrict__ wg, const float* __restrict__ bg,
    unsigned short* __restrict__ y)
{
  __shared__ float Gs[64][52];
  __shared__ float Ws[48][52];
  const int tid = threadIdx.x;
  const int rt = blockIdx.x, ct = blockIdx.y;
  const int n0g = rt * 64;
  const int g = ct >> 1;
  const int dd0 = ct * 48;
  const float* src = (g < 2) ? h : df;
  const int cb = (g & 1) * CG;
  const int ty = tid >> 4, tx = tid & 15;
  float acc[4][3] = {};
  for (int k0 = 0; k0 < CG; k0 += 48) {
    __syncthreads();
#pragma unroll
    for (int p = 0; p < 3; ++p) {
      int e = tid + p * 256;
      int r = e / 12, c4 = (e % 12) * 4;
      *(float4*)&Gs[r][c4] = *(const float4*)&src[(size_t)(n0g + r) * CH + cb + k0 + c4];
    }
    for (int e = tid; e < 2304; e += 256) {
      int dd = e / 48, kk = e % 48;
      Ws[dd][kk] = wg[(size_t)(dd0 + dd) * CG + k0 + kk];
    }
    __syncthreads();
#pragma unroll
    for (int kq = 0; kq < 12; ++kq) {
      float4 av[4], bv[3];
#pragma unroll
      for (int i = 0; i < 4; ++i) av[i] = *(const float4*)&Gs[ty*4 + i][kq*4];
#pragma unroll
      for (int j = 0; j < 3; ++j) bv[j] = *(const float4*)&Ws[tx*3 + j][kq*4];
#pragma unroll
      for (int i = 0; i < 4; ++i)
#pragma unroll
        for (int j = 0; j < 3; ++j)
          acc[i][j] += av[i].x*bv[j].x + av[i].y*bv[j].y + av[i].z*bv[j].z + av[i].w*bv[j].w;
    }
  }
#pragma unroll
  for (int i = 0; i < 4; ++i) {
    int row = n0g + ty*4 + i;
#pragma unroll
    for (int j = 0; j < 3; ++j) {
      int oc = dd0 + tx*3 + j;
      float v = acc[i][j] + bg[oc];
      y[(size_t)row * C2 + oc] = f2bf(gelu_exact(v));
    }
  }
}

// ---------------- K5: fc2 + BN2 + residual (bf16 y input) ----------------
__global__ __launch_bounds__(256) void fc2_kernel(
    const unsigned short* __restrict__ yv, const float* __restrict__ w2,
    const float* __restrict__ b2, const float* __restrict__ x, float* __restrict__ out)
{
  __shared__ float As[64*68];
  __shared__ float Bs[64*68];
  __shared__ float Os[64*68];
  const int tid = threadIdx.x;
  const int rt = blockIdx.x, dt = blockIdx.y;
  const int n0g = rt * 64;
  const int b = n0g / NPTS;
  const int nloc0 = n0g - b * NPTS;
  const int d0 = dt * 64;
  const int ty = tid >> 4, tx = tid & 15;
  float acc[4][4] = {};
  for (int k0 = 0; k0 < C2; k0 += 64) {
    if (k0) __syncthreads();
#pragma unroll
    for (int p = 0; p < 2; ++p) {
      int e = p * 256 + tid;
      int r = e >> 3, k8 = (e & 7) * 8;
      uint4 v = *(const uint4*)&yv[(size_t)(n0g + r) * C2 + k0 + k8];
      const unsigned short* u = (const unsigned short*)&v;
#pragma unroll
      for (int j = 0; j < 8; ++j) As[r*68 + k8 + j] = bf2f(u[j]);
    }
#pragma unroll
    for (int p = 0; p < 4; ++p) {
      int e = p * 256 + tid;
      int dd = e >> 4, k4 = (e & 15) << 2;
      *(float4*)&Bs[dd*68 + k4] = *(const float4*)&w2[(size_t)(d0 + dd) * C2 + k0 + k4];
    }
    __syncthreads();
#pragma unroll
    for (int kq = 0; kq < 16; ++kq) {
      float4 av[4], bv[4];
#pragma unroll
      for (int i = 0; i < 4; ++i) av[i] = *(const float4*)&As[(ty*4+i)*68 + kq*4];
#pragma unroll
      for (int j = 0; j < 4; ++j) bv[j] = *(const float4*)&Bs[(tx*4+j)*68 + kq*4];
#pragma unroll
      for (int i = 0; i < 4; ++i)
#pragma unroll
        for (int j = 0; j < 4; ++j)
          acc[i][j] += av[i].x*bv[j].x + av[i].y*bv[j].y + av[i].z*bv[j].z + av[i].w*bv[j].w;
    }
  }
  __syncthreads();
#pragma unroll
  for (int i = 0; i < 4; ++i)
#pragma unroll
    for (int j = 0; j < 4; ++j)
      Os[(tx*4 + j)*68 + ty*4 + i] = acc[i][j];
  __syncthreads();
#pragma unroll
  for (int p = 0; p < 4; ++p) {
    int cl = (tid >> 4) + p * 16;
    int n4 = (tid & 15) << 2;
    float4 v = *(const float4*)&Os[cl*68 + n4];
    size_t gi = ((size_t)b * CH + d0 + cl) * NPTS + nloc0 + n4;
    float bb = b2[d0 + cl];
    float4 xr = *(const float4*)&x[gi];
    v.x += bb + xr.x; v.y += bb + xr.y; v.z += bb + xr.z; v.w += bb + xr.w;
    *(float4*)&out[gi] = v;
  }
}

extern "C" void kernel_launch(void* const* d_in, const int* in_sizes, int n_in,
                              void* d_out, int out_size, void* d_ws, size_t ws_size,
                              hipStream_t stream) {
  const float* x     = (const float*)d_in[0];
  const float* fc1_w = (const float*)d_in[1];
  const float* fc1_b = (const float*)d_in[2];
  const float* bn1_g = (const float*)d_in[3];
  const float* bn1_b = (const float*)d_in[4];
  const float* bn1_m = (const float*)d_in[5];
  const float* bn1_v = (const float*)d_in[6];
  const float* gc_w  = (const float*)d_in[7];
  const float* gc_b  = (const float*)d_in[8];
  const float* bng_g = (const float*)d_in[9];
  const float* bng_b = (const float*)d_in[10];
  const float* bng_m = (const float*)d_in[11];
  const float* bng_v = (const float*)d_in[12];
  const float* fc2_w = (const float*)d_in[13];
  const float* fc2_b = (const float*)d_in[14];
  const float* bn2_g = (const float*)d_in[15];
  const float* bn2_b = (const float*)d_in[16];
  const float* bn2_m = (const float*)d_in[17];
  const float* bn2_v = (const float*)d_in[18];

  float* ws = (float*)d_ws;
  size_t o = 0;
  float* W1 = ws + o; o += 36864;
  float* B1 = ws + o; o += 192;
  float* WG = ws + o; o += 36864;
  float* BG = ws + o; o += 384;
  float* W2 = ws + o; o += 73728;
  float* B2 = ws + o; o += 192;
  float* FT = ws + o; o += 64;
  float* H  = ws + o; o += (size_t)25088 * 192;     // 4,816,896 f32
  float* SQ = ws + o; o += 25088;
  int*   NN = (int*)(ws + o); o += 25088 * 9;
  float* SCR = ws + o;
  unsigned short* XHI = (unsigned short*)SCR;                    // 4,816,896 u16
  unsigned short* XLO = XHI + (size_t)25088 * 192;               // 4,816,896 u16
  float* DF  = SCR;                                              // overlays XHI+XLO (exact fit)
  float* XN  = SCR + (size_t)4816896;                            // 4,816,896 f32
  unsigned short* YB = (unsigned short*)XN;                      // overlays XN (exact fit)
  float* PD  = XN + (size_t)4816896;                             // 25088*24 f32
  int*   PI  = (int*)(PD + (size_t)25088 * NCAND);               // 25088*24 int
  (void)ws_size; (void)in_sizes; (void)n_in; (void)out_size;

  hipLaunchKernelGGL(prep_kernel, dim3(580), dim3(256), 0, stream,
                     fc1_w, fc1_b, bn1_g, bn1_b, bn1_m, bn1_v,
                     gc_w, gc_b, bng_g, bng_b, bng_m, bng_v,
                     fc2_w, fc2_b, bn2_g, bn2_b, bn2_m, bn2_v,
                     W1, B1, WG, BG, W2, B2, FT);
  hipLaunchKernelGGL(fc1_kernel, dim3(49, 3, 8), dim3(256), 0, stream, x, W1, B1, H);
  hipLaunchKernelGGL(norm_kernel, dim3(6272), dim3(256), 0, stream, H, XN, XHI, XLO, SQ);
  hipLaunchKernelGGL(topk_kernel, dim3(49, 2, 8), dim3(256), 0, stream, XHI, XLO, FT, PD, PI);
  hipLaunchKernelGGL(refine_kernel, dim3(6272), dim3(256), 0, stream, PD, PI, XN, SQ, FT, NN);
  hipLaunchKernelGGL(edge_kernel, dim3(392), dim3(256), 0, stream, H, NN, DF);
  hipLaunchKernelGGL(gc_kernel, dim3(392, 8), dim3(256), 0, stream, H, DF, WG, BG, YB);
  hipLaunchKernelGGL(fc2_kernel, dim3(392, 3), dim3(256), 0, stream, YB, W2, B2, x, (float*)d_out);
}

// Round 5
// 1441.846 us; speedup vs baseline: 2.4450x; 1.0380x over previous
//
#include <hip/hip_runtime.h>
#include <math.h>

#define BATCH 8
#define CH    192
#define WW    56
#define NPTS  3136
#define C2    384
#define CG    96
#define MT    32
#define LK    12
#define NCAND 24
#define NREF  16

typedef float f32x4 __attribute__((ext_vector_type(4)));
typedef short bf16x8 __attribute__((ext_vector_type(8)));

__device__ __forceinline__ float gelu_exact(float v) {
  return 0.5f * v * (1.0f + erff(v * 0.7071067811865475f));
}
__device__ __forceinline__ unsigned short f2bf(float f) {
  unsigned int u = __float_as_uint(f);
  u = u + 0x7fffu + ((u >> 16) & 1u);
  return (unsigned short)(u >> 16);
}
__device__ __forceinline__ float bf2f(unsigned short h) {
  return __uint_as_float(((unsigned int)h) << 16);
}
__device__ __forceinline__ void gl_lds16(const void* g, void* lds) {
  __builtin_amdgcn_global_load_lds(
      (const __attribute__((address_space(1))) unsigned int*)g,
      (__attribute__((address_space(3))) unsigned int*)lds, 16, 0, 0);
}

// ---------------- K0: fold BN into weights, build scaled cos-table ----------------
__global__ void prep_kernel(
    const float* __restrict__ fc1_w, const float* __restrict__ fc1_b,
    const float* __restrict__ bn1_g, const float* __restrict__ bn1_b,
    const float* __restrict__ bn1_m, const float* __restrict__ bn1_v,
    const float* __restrict__ gc_w,  const float* __restrict__ gc_b,
    const float* __restrict__ bng_g, const float* __restrict__ bng_b,
    const float* __restrict__ bng_m, const float* __restrict__ bng_v,
    const float* __restrict__ fc2_w, const float* __restrict__ fc2_b,
    const float* __restrict__ bn2_g, const float* __restrict__ bn2_b,
    const float* __restrict__ bn2_m, const float* __restrict__ bn2_v,
    float* __restrict__ w1, float* __restrict__ b1,
    float* __restrict__ wg, float* __restrict__ bg,
    float* __restrict__ w2, float* __restrict__ b2,
    float* __restrict__ ftab)
{
  int i = blockIdx.x * 256 + threadIdx.x;
  if (i < 36864) {
    int d = i / CH;
    float s = bn1_g[d] / sqrtf(bn1_v[d] + 1e-5f);
    w1[i] = fc1_w[i] * s;
  } else if (i < 37056) {
    int d = i - 36864;
    float s = bn1_g[d] / sqrtf(bn1_v[d] + 1e-5f);
    b1[d] = (fc1_b[d] - bn1_m[d]) * s + bn1_b[d];
  } else if (i < 73920) {
    int j = i - 37056;
    int o = j / CG;
    float s = bng_g[o] / sqrtf(bng_v[o] + 1e-5f);
    wg[j] = gc_w[j] * s;
  } else if (i < 74304) {
    int o = i - 73920;
    float s = bng_g[o] / sqrtf(bng_v[o] + 1e-5f);
    bg[o] = (gc_b[o] - bng_m[o]) * s + bng_b[o];
  } else if (i < 148032) {
    int j = i - 74304;
    int d = j / C2;
    float s = bn2_g[d] / sqrtf(bn2_v[d] + 1e-5f);
    w2[j] = fc2_w[j] * s;
  } else if (i < 148224) {
    int d = i - 148032;
    float s = bn2_g[d] / sqrtf(bn2_v[d] + 1e-5f);
    b2[d] = (fc2_b[d] - bn2_m[d]) * s + bn2_b[d];
  } else if (i < 148280) {
    int delta = i - 148224;
    float s = 0.f;
    for (int t = 0; t < 48; ++t) {
      float omega = powf(10000.f, -(float)t / 48.f);
      s += cosf((float)delta * omega);
    }
    ftab[delta] = s * (-2.0f / (float)CH);   // pre-scaled: rel = ft[dy]+ft[dx]
  }
}

// ---------------- K1: h = BN1(fc1(x^T)) ; h layout [b][n][c] ----------------
__global__ __launch_bounds__(256) void fc1_kernel(
    const float* __restrict__ x, const float* __restrict__ w1,
    const float* __restrict__ b1, float* __restrict__ h)
{
  __shared__ float As[64*68];
  __shared__ float Bs[64*68];
  const int tid = threadIdx.x;
  const int ntile = blockIdx.x, dt = blockIdx.y, b = blockIdx.z;
  const int n0 = ntile * 64, d0 = dt * 64;
  const int ty = tid >> 4, tx = tid & 15;
  const float* xb = x + (size_t)b * CH * NPTS;
  float acc[4][4] = {};
  for (int k0 = 0; k0 < CH; k0 += 64) {
    if (k0) __syncthreads();
#pragma unroll
    for (int p = 0; p < 16; ++p) {
      int e = p * 256 + tid;
      int kk = e >> 6, r = e & 63;
      As[r*68 + kk] = xb[(size_t)(k0 + kk) * NPTS + n0 + r];
    }
#pragma unroll
    for (int p = 0; p < 4; ++p) {
      int e = p * 256 + tid;
      int dd = e >> 4, k4 = (e & 15) << 2;
      *(float4*)&Bs[dd*68 + k4] = *(const float4*)&w1[(size_t)(d0 + dd) * CH + k0 + k4];
    }
    __syncthreads();
#pragma unroll
    for (int kq = 0; kq < 16; ++kq) {
      float4 av[4], bv[4];
#pragma unroll
      for (int i = 0; i < 4; ++i) av[i] = *(const float4*)&As[(ty*4+i)*68 + kq*4];
#pragma unroll
      for (int j = 0; j < 4; ++j) bv[j] = *(const float4*)&Bs[(tx*4+j)*68 + kq*4];
#pragma unroll
      for (int i = 0; i < 4; ++i)
#pragma unroll
        for (int j = 0; j < 4; ++j)
          acc[i][j] += av[i].x*bv[j].x + av[i].y*bv[j].y + av[i].z*bv[j].z + av[i].w*bv[j].w;
    }
  }
#pragma unroll
  for (int i = 0; i < 4; ++i) {
    int n = n0 + ty*4 + i;
    float4 v;
    v.x = acc[i][0] + b1[d0 + tx*4 + 0];
    v.y = acc[i][1] + b1[d0 + tx*4 + 1];
    v.z = acc[i][2] + b1[d0 + tx*4 + 2];
    v.w = acc[i][3] + b1[d0 + tx*4 + 3];
    *(float4*)&h[((size_t)b * NPTS + n) * CH + d0 + tx*4] = v;
  }
}

// ---------------- K2: xn (f32 + bf16 hi/lo split) + sq ----------------
__global__ __launch_bounds__(256) void norm_kernel(
    const float* __restrict__ h, float* __restrict__ xnf,
    unsigned short* __restrict__ xhi, unsigned short* __restrict__ xlo,
    float* __restrict__ sqv)
{
  const int lane = threadIdx.x & 63;
  const int row = blockIdx.x * 4 + (threadIdx.x >> 6);
  const float* hr = h + (size_t)row * CH;
  float v0 = hr[lane], v1 = hr[lane + 64], v2 = hr[lane + 128];
  float s = v0*v0 + v1*v1 + v2*v2;
#pragma unroll
  for (int o = 32; o > 0; o >>= 1) s += __shfl_xor(s, o);
  float inv = 1.0f / fmaxf(sqrtf(s), 1e-12f);
  float x0 = v0 * inv, x1 = v1 * inv, x2 = v2 * inv;
  size_t base = (size_t)row * CH;
  xnf[base + lane      ] = x0;
  xnf[base + lane + 64 ] = x1;
  xnf[base + lane + 128] = x2;
  unsigned short h0 = f2bf(x0), h1 = f2bf(x1), h2 = f2bf(x2);
  xhi[base + lane      ] = h0;
  xhi[base + lane + 64 ] = h1;
  xhi[base + lane + 128] = h2;
  xlo[base + lane      ] = f2bf(x0 - bf2f(h0));
  xlo[base + lane + 64 ] = f2bf(x1 - bf2f(h1));
  xlo[base + lane + 128] = f2bf(x2 - bf2f(h2));
  if (lane == 0) sqv[row] = s * inv * inv;
}

// ---------------- K3: MFMA coarse dist, per-lane register top-12 ----------------
// grid (49, 2, 8); 256 thr = 4 waves. Wave w owns 16 n; m streams in 32-row tiles.
// Staging: global_load_lds (async DMA), LDS linear dest + inverse-swizzled global
// source; ds_read applies the same XOR. Double-buffered; 49 KB LDS pins 3 blk/CU
// so the allocator budget is 168 VGPR -> no scratch spill (round-4 killer).
__global__ __launch_bounds__(256, 3) void topk_kernel(
    const unsigned short* __restrict__ xhi, const unsigned short* __restrict__ xlo,
    const float* __restrict__ fts_g,
    float* __restrict__ pd, int* __restrict__ pi)
{
  __shared__ __align__(16) char LDSbuf[2 * 24576];   // [buf][hi 12288 | lo 12288]
  __shared__ float ft[56];

  const int tid  = threadIdx.x;
  const int lane = tid & 63;
  const int w    = tid >> 6;
  const int nt = blockIdx.x, ms = blockIdx.y, b = blockIdx.z;
  const int n0 = nt * 64;
  const size_t rowbase = (size_t)b * NPTS;

  if (tid < 56) ft[tid] = fts_g[tid];

  const int ar = lane & 15;
  const int hi = lane >> 4;
  const int ak = hi * 8;

  // B fragments (n-side) in registers
  const int n_b = n0 + w * 16 + ar;
  bf16x8 bhi[6], blo[6];
  {
    const unsigned short* pbh = xhi + (rowbase + n_b) * CH + ak;
    const unsigned short* pbl = xlo + (rowbase + n_b) * CH + ak;
#pragma unroll
    for (int c = 0; c < 6; ++c) {
      bhi[c] = *(const bf16x8*)(pbh + c * 32);
      blo[c] = *(const bf16x8*)(pbl + c * 32);
    }
  }
  const int yn_l = n_b / WW, xn_l = n_b % WW;

  float ld[LK]; int li[LK];
#pragma unroll
  for (int k = 0; k < LK; ++k) { ld[k] = INFINITY; li[k] = 0x7fffffff; }

  // per-lane DMA source offsets (constant across tiles): 6 chunks of 16B per lane.
  // LDS linear slot L -> source byte r*384 + (off ^ swz(r))  (XOR involution)
  int srcb[6];
#pragma unroll
  for (int j = 0; j < 6; ++j) {
    int L = (w & 1) * 6144 + j * 1024 + lane * 16;   // within 12288 region
    int r = L / 384, off = L % 384;
    srcb[j] = r * 384 + (off ^ ((r & 7) << 4));
  }
  const int ldsb = (w >= 2 ? 12288 : 0) + (w & 1) * 6144;  // wave-uniform dest base

  const int mbase = ms * (NPTS / 2);     // 0 or 1568 = 28*56
  // per-wave global byte base (hi array for waves 0-1, lo for waves 2-3)
  const char* gb = (w < 2 ? (const char*)xhi : (const char*)xlo)
                   + (rowbase + mbase) * (CH * 2);

#define STAGE(BUF) do {                                                     \
  _Pragma("unroll")                                                         \
  for (int j = 0; j < 6; ++j)                                               \
    gl_lds16(gb + srcb[j], LDSbuf + (BUF) * 24576 + ldsb + j * 1024);       \
} while (0)

  STAGE(0);
  gb += 12288;

  int ym0 = ms * 28, xm0 = 0;            // coords of m0, updated incrementally

  for (int tt = 0; tt < 49; ++tt) {
    __syncthreads();                     // drains vmcnt -> buf[tt&1] staged; prior reads done
    if (tt + 1 < 49) { STAGE((tt + 1) & 1); gb += 12288; }

    const int m0 = mbase + tt * MT;
    const int bufb = (tt & 1) * 24576;
    // MFMA: D[m(32) x n(16)]; acc col = n (fixed per lane), rows = m
    f32x4 acc[2] = {};
#pragma unroll
    for (int rt = 0; rt < 2; ++rt) {
      const int rA = rt * 16 + ar;
      const int swz = (rA & 7) << 4;
#pragma unroll
      for (int c = 0; c < 6; ++c) {
        int off = bufb + rA * 384 + ((c * 64 + hi * 16) ^ swz);
        bf16x8 ah = *(const bf16x8*)(LDSbuf + off);
        bf16x8 al = *(const bf16x8*)(LDSbuf + off + 12288);
        acc[rt] = __builtin_amdgcn_mfma_f32_16x16x32_bf16(ah, bhi[c], acc[rt], 0, 0, 0);
        acc[rt] = __builtin_amdgcn_mfma_f32_16x16x32_bf16(ah, blo[c], acc[rt], 0, 0, 0);
        acc[rt] = __builtin_amdgcn_mfma_f32_16x16x32_bf16(al, bhi[c], acc[rt], 0, 0, 0);
      }
    }
    // epilogue: 8 values per lane, m = m0 + rt*16 + hi*4 + i
#pragma unroll
    for (int rt = 0; rt < 2; ++rt) {
#pragma unroll
      for (int i = 0; i < 4; ++i) {
        const int off_m = rt * 16 + hi * 4 + i;
        int xm = xm0 + off_m, ym = ym0;
        if (xm >= WW) { xm -= WW; ym += 1; }
        int dy = yn_l - ym; dy = dy < 0 ? -dy : dy;
        int dx = xn_l - xm; dx = dx < 0 ? -dx : dx;
        float d_ = ft[dy] + ft[dx] - 2.0f * acc[rt][i];
        if (d_ < ld[LK-1]) {
          float cd = d_; int ci = m0 + off_m;
#pragma unroll
          for (int s = 0; s < LK; ++s) {
            if (cd < ld[s]) { float t0=ld[s]; int t1=li[s]; ld[s]=cd; li[s]=ci; cd=t0; ci=t1; }
          }
        }
      }
    }
    xm0 += MT;
    if (xm0 >= WW) { xm0 -= WW; ym0 += 1; }
  }

  // tail: 4-way merge per n (hi-lanes 0..3), write top-12 per (n, ms)
  __syncthreads();
  float* Md = (float*)LDSbuf;                 // 256*12*4 = 12288 B
  int*   Mi = (int*)(LDSbuf + 12288);
#pragma unroll
  for (int k = 0; k < LK; ++k) { Md[tid * LK + k] = ld[k]; Mi[tid * LK + k] = li[k]; }
  __syncthreads();
  if (tid < 64) {
    const int wv = tid >> 4, arr = tid & 15;
    const int n = n0 + tid;
    int lb[4];
#pragma unroll
    for (int hq = 0; hq < 4; ++hq) lb[hq] = (wv * 64 + hq * 16 + arr) * LK;
    int p0 = 0, p1 = 0, p2 = 0, p3 = 0;
    float* od = pd + ((rowbase + n) * 2 + ms) * LK;
    int*   oi = pi + ((rowbase + n) * 2 + ms) * LK;
    for (int k = 0; k < LK; ++k) {
      float bd = Md[lb[0] + p0]; int bi = Mi[lb[0] + p0]; int bq = 0;
      float dv = Md[lb[1] + p1]; int iv = Mi[lb[1] + p1];
      if (dv < bd || (dv == bd && iv < bi)) { bd = dv; bi = iv; bq = 1; }
      dv = Md[lb[2] + p2]; iv = Mi[lb[2] + p2];
      if (dv < bd || (dv == bd && iv < bi)) { bd = dv; bi = iv; bq = 2; }
      dv = Md[lb[3] + p3]; iv = Mi[lb[3] + p3];
      if (dv < bd || (dv == bd && iv < bi)) { bd = dv; bi = iv; bq = 3; }
      if (bq == 0) { if (p0 < LK-1) ++p0; else Md[lb[0]+p0] = INFINITY; }
      else if (bq == 1) { if (p1 < LK-1) ++p1; else Md[lb[1]+p1] = INFINITY; }
      else if (bq == 2) { if (p2 < LK-1) ++p2; else Md[lb[2]+p2] = INFINITY; }
      else              { if (p3 < LK-1) ++p3; else Md[lb[3]+p3] = INFINITY; }
      od[k] = bd; oi[k] = bi;
    }
  }
#undef STAGE
}

// ---------------- K3b: pool 24 coarse candidates -> exact f32 refine -> top-9 ----------------
__global__ __launch_bounds__(256) void refine_kernel(
    const float* __restrict__ pd, const int* __restrict__ pi,
    const float* __restrict__ xn, const float* __restrict__ sqv,
    const float* __restrict__ fts_g, int* __restrict__ nn)
{
  __shared__ float alld[4][NCAND];
  __shared__ int   alli[4][NCAND];
  __shared__ int   ci_s[4][NREF];
  __shared__ float ft[56];
  const int tid = threadIdx.x;
  const int w = tid >> 6, lane = tid & 63;
  if (tid < 56) ft[tid] = fts_g[tid];
  const int row = blockIdx.x * 4 + w;
  const int b = row / NPTS;
  const int n_loc = row - b * NPTS;

  if (lane < NCAND) {
    alld[w][lane] = pd[(size_t)row * NCAND + lane];
    alli[w][lane] = pi[(size_t)row * NCAND + lane];
  }
  __syncthreads();
  if (lane < NCAND) {
    float d0 = alld[w][lane]; int i0 = alli[w][lane];
    int rank = 0;
    for (int j = 0; j < NCAND; ++j) {
      float dj = alld[w][j]; int ij = alli[w][j];
      rank += (dj < d0 || (dj == d0 && ij < i0)) ? 1 : 0;
    }
    if (rank < NREF) ci_s[w][rank] = i0;
  }
  __syncthreads();

  const float* xrow = xn + (size_t)row * CH;
  float a0 = xrow[lane], a1 = xrow[lane + 64], a2 = xrow[lane + 128];
  const int yn_ = n_loc / WW, xq_ = n_loc % WW;
  const size_t xbase = (size_t)b * NPTS * CH;
  float myd = INFINITY; int myi = 0x7fffffff;
#pragma unroll 4
  for (int c = 0; c < NREF; ++c) {
    int m = ci_s[w][c];
    const float* xm = xn + xbase + (size_t)m * CH;
    float s = a0 * xm[lane] + a1 * xm[lane + 64] + a2 * xm[lane + 128];
#pragma unroll
    for (int o = 32; o > 0; o >>= 1) s += __shfl_xor(s, o);
    if (lane == c) {
      int ym = m / WW, xm_ = m % WW;
      int dy = yn_ - ym; dy = dy < 0 ? -dy : dy;
      int dx = xq_ - xm_; dx = dx < 0 ? -dx : dx;
      myd = sqv[(size_t)b * NPTS + m] - 2.0f * s + (ft[dy] + ft[dx]);
      myi = m;
    }
  }
  if (lane < NREF) {
    int rank = 0;
    for (int j = 0; j < NREF; ++j) {
      float dj = __shfl(myd, j); int ij = __shfl(myi, j);
      rank += (dj < myd || (dj == myd && ij < myi)) ? 1 : 0;
    }
    if (rank < 9) nn[(size_t)row * 9 + rank] = myi;
  }
}

// ---------------- K3c: edge features d = max_j(x_j) - h, once ----------------
__global__ __launch_bounds__(256) void edge_kernel(
    const float* __restrict__ h, const int* __restrict__ nn,
    float* __restrict__ df)
{
  __shared__ int nns[576];
  const int n0g = blockIdx.x * 64;
  const int b = n0g / NPTS;
  const size_t rowbase = (size_t)b * NPTS;
  const int tid = threadIdx.x;
  for (int e = tid; e < 576; e += 256)
    nns[e] = nn[(size_t)(n0g + e / 9) * 9 + (e % 9)];
  __syncthreads();
#pragma unroll
  for (int p = 0; p < 12; ++p) {
    int e = tid + 256 * p;
    int r = e / 48, c4 = (e % 48) * 4;
    float4 hv = *(const float4*)&h[(size_t)(n0g + r) * CH + c4];
    float4 mx = make_float4(-INFINITY, -INFINITY, -INFINITY, -INFINITY);
#pragma unroll
    for (int k = 0; k < 9; ++k) {
      float4 nv = *(const float4*)&h[(rowbase + nns[r*9 + k]) * CH + c4];
      mx.x = fmaxf(mx.x, nv.x); mx.y = fmaxf(mx.y, nv.y);
      mx.z = fmaxf(mx.z, nv.z); mx.w = fmaxf(mx.w, nv.w);
    }
    float4 ov;
    ov.x = mx.x - hv.x; ov.y = mx.y - hv.y; ov.z = mx.z - hv.z; ov.w = mx.w - hv.w;
    *(float4*)&df[(size_t)(n0g + r) * CH + c4] = ov;
  }
}

// ---------------- K4: grouped GEMM + GELU (no gathers), y in bf16 ----------------
__global__ __launch_bounds__(256) void gc_kernel(
    const float* __restrict__ h, const float* __restrict__ df,
    const float* __restrict__ wg, const float* __restrict__ bg,
    unsigned short* __restrict__ y)
{
  __shared__ float Gs[64][52];
  __shared__ float Ws[48][52];
  const int tid = threadIdx.x;
  const int rt = blockIdx.x, ct = blockIdx.y;
  const int n0g = rt * 64;
  const int g = ct >> 1;
  const int dd0 = ct * 48;
  const float* src = (g < 2) ? h : df;
  const int cb = (g & 1) * CG;
  const int ty = tid >> 4, tx = tid & 15;
  float acc[4][3] = {};
  for (int k0 = 0; k0 < CG; k0 += 48) {
    __syncthreads();
#pragma unroll
    for (int p = 0; p < 3; ++p) {
      int e = tid + p * 256;
      int r = e / 12, c4 = (e % 12) * 4;
      *(float4*)&Gs[r][c4] = *(const float4*)&src[(size_t)(n0g + r) * CH + cb + k0 + c4];
    }
    for (int e = tid; e < 2304; e += 256) {
      int dd = e / 48, kk = e % 48;
      Ws[dd][kk] = wg[(size_t)(dd0 + dd) * CG + k0 + kk];
    }
    __syncthreads();
#pragma unroll
    for (int kq = 0; kq < 12; ++kq) {
      float4 av[4], bv[3];
#pragma unroll
      for (int i = 0; i < 4; ++i) av[i] = *(const float4*)&Gs[ty*4 + i][kq*4];
#pragma unroll
      for (int j = 0; j < 3; ++j) bv[j] = *(const float4*)&Ws[tx*3 + j][kq*4];
#pragma unroll
      for (int i = 0; i < 4; ++i)
#pragma unroll
        for (int j = 0; j < 3; ++j)
          acc[i][j] += av[i].x*bv[j].x + av[i].y*bv[j].y + av[i].z*bv[j].z + av[i].w*bv[j].w;
    }
  }
#pragma unroll
  for (int i = 0; i < 4; ++i) {
    int row = n0g + ty*4 + i;
#pragma unroll
    for (int j = 0; j < 3; ++j) {
      int oc = dd0 + tx*3 + j;
      float v = acc[i][j] + bg[oc];
      y[(size_t)row * C2 + oc] = f2bf(gelu_exact(v));
    }
  }
}

// ---------------- K5: fc2 + BN2 + residual (bf16 y input) ----------------
__global__ __launch_bounds__(256) void fc2_kernel(
    const unsigned short* __restrict__ yv, const float* __restrict__ w2,
    const float* __restrict__ b2, const float* __restrict__ x, float* __restrict__ out)
{
  __shared__ float As[64*68];
  __shared__ float Bs[64*68];
  __shared__ float Os[64*68];
  const int tid = threadIdx.x;
  const int rt = blockIdx.x, dt = blockIdx.y;
  const int n0g = rt * 64;
  const int b = n0g / NPTS;
  const int nloc0 = n0g - b * NPTS;
  const int d0 = dt * 64;
  const int ty = tid >> 4, tx = tid & 15;
  float acc[4][4] = {};
  for (int k0 = 0; k0 < C2; k0 += 64) {
    if (k0) __syncthreads();
#pragma unroll
    for (int p = 0; p < 2; ++p) {
      int e = p * 256 + tid;
      int r = e >> 3, k8 = (e & 7) * 8;
      uint4 v = *(const uint4*)&yv[(size_t)(n0g + r) * C2 + k0 + k8];
      const unsigned short* u = (const unsigned short*)&v;
#pragma unroll
      for (int j = 0; j < 8; ++j) As[r*68 + k8 + j] = bf2f(u[j]);
    }
#pragma unroll
    for (int p = 0; p < 4; ++p) {
      int e = p * 256 + tid;
      int dd = e >> 4, k4 = (e & 15) << 2;
      *(float4*)&Bs[dd*68 + k4] = *(const float4*)&w2[(size_t)(d0 + dd) * C2 + k0 + k4];
    }
    __syncthreads();
#pragma unroll
    for (int kq = 0; kq < 16; ++kq) {
      float4 av[4], bv[4];
#pragma unroll
      for (int i = 0; i < 4; ++i) av[i] = *(const float4*)&As[(ty*4+i)*68 + kq*4];
#pragma unroll
      for (int j = 0; j < 4; ++j) bv[j] = *(const float4*)&Bs[(tx*4+j)*68 + kq*4];
#pragma unroll
      for (int i = 0; i < 4; ++i)
#pragma unroll
        for (int j = 0; j < 4; ++j)
          acc[i][j] += av[i].x*bv[j].x + av[i].y*bv[j].y + av[i].z*bv[j].z + av[i].w*bv[j].w;
    }
  }
  __syncthreads();
#pragma unroll
  for (int i = 0; i < 4; ++i)
#pragma unroll
    for (int j = 0; j < 4; ++j)
      Os[(tx*4 + j)*68 + ty*4 + i] = acc[i][j];
  __syncthreads();
#pragma unroll
  for (int p = 0; p < 4; ++p) {
    int cl = (tid >> 4) + p * 16;
    int n4 = (tid & 15) << 2;
    float4 v = *(const float4*)&Os[cl*68 + n4];
    size_t gi = ((size_t)b * CH + d0 + cl) * NPTS + nloc0 + n4;
    float bb = b2[d0 + cl];
    float4 xr = *(const float4*)&x[gi];
    v.x += bb + xr.x; v.y += bb + xr.y; v.z += bb + xr.z; v.w += bb + xr.w;
    *(float4*)&out[gi] = v;
  }
}

extern "C" void kernel_launch(void* const* d_in, const int* in_sizes, int n_in,
                              void* d_out, int out_size, void* d_ws, size_t ws_size,
                              hipStream_t stream) {
  const float* x     = (const float*)d_in[0];
  const float* fc1_w = (const float*)d_in[1];
  const float* fc1_b = (const float*)d_in[2];
  const float* bn1_g = (const float*)d_in[3];
  const float* bn1_b = (const float*)d_in[4];
  const float* bn1_m = (const float*)d_in[5];
  const float* bn1_v = (const float*)d_in[6];
  const float* gc_w  = (const float*)d_in[7];
  const float* gc_b  = (const float*)d_in[8];
  const float* bng_g = (const float*)d_in[9];
  const float* bng_b = (const float*)d_in[10];
  const float* bng_m = (const float*)d_in[11];
  const float* bng_v = (const float*)d_in[12];
  const float* fc2_w = (const float*)d_in[13];
  const float* fc2_b = (const float*)d_in[14];
  const float* bn2_g = (const float*)d_in[15];
  const float* bn2_b = (const float*)d_in[16];
  const float* bn2_m = (const float*)d_in[17];
  const float* bn2_v = (const float*)d_in[18];

  float* ws = (float*)d_ws;
  size_t o = 0;
  float* W1 = ws + o; o += 36864;
  float* B1 = ws + o; o += 192;
  float* WG = ws + o; o += 36864;
  float* BG = ws + o; o += 384;
  float* W2 = ws + o; o += 73728;
  float* B2 = ws + o; o += 192;
  float* FT = ws + o; o += 64;
  float* H  = ws + o; o += (size_t)25088 * 192;     // 4,816,896 f32
  float* SQ = ws + o; o += 25088;
  int*   NN = (int*)(ws + o); o += 25088 * 9;
  float* SCR = ws + o;
  unsigned short* XHI = (unsigned short*)SCR;                    // 4,816,896 u16
  unsigned short* XLO = XHI + (size_t)25088 * 192;               // 4,816,896 u16
  float* DF  = SCR;                                              // overlays XHI+XLO (exact fit)
  float* XN  = SCR + (size_t)4816896;                            // 4,816,896 f32
  unsigned short* YB = (unsigned short*)XN;                      // overlays XN (exact fit)
  float* PD  = XN + (size_t)4816896;                             // 25088*24 f32
  int*   PI  = (int*)(PD + (size_t)25088 * NCAND);               // 25088*24 int
  (void)ws_size; (void)in_sizes; (void)n_in; (void)out_size;

  hipLaunchKernelGGL(prep_kernel, dim3(580), dim3(256), 0, stream,
                     fc1_w, fc1_b, bn1_g, bn1_b, bn1_m, bn1_v,
                     gc_w, gc_b, bng_g, bng_b, bng_m, bng_v,
                     fc2_w, fc2_b, bn2_g, bn2_b, bn2_m, bn2_v,
                     W1, B1, WG, BG, W2, B2, FT);
  hipLaunchKernelGGL(fc1_kernel, dim3(49, 3, 8), dim3(256), 0, stream, x, W1, B1, H);
  hipLaunchKernelGGL(norm_kernel, dim3(6272), dim3(256), 0, stream, H, XN, XHI, XLO, SQ);
  hipLaunchKernelGGL(topk_kernel, dim3(49, 2, 8), dim3(256), 0, stream, XHI, XLO, FT, PD, PI);
  hipLaunchKernelGGL(refine_kernel, dim3(6272), dim3(256), 0, stream, PD, PI, XN, SQ, FT, NN);
  hipLaunchKernelGGL(edge_kernel, dim3(392), dim3(256), 0, stream, H, NN, DF);
  hipLaunchKernelGGL(gc_kernel, dim3(392, 8), dim3(256), 0, stream, H, DF, WG, BG, YB);
  hipLaunchKernelGGL(fc2_kernel, dim3(392, 3), dim3(256), 0, stream, YB, W2, B2, x, (float*)d_out);
}

// Round 6
// 1230.665 us; speedup vs baseline: 2.8645x; 1.1716x over previous
//
#include <hip/hip_runtime.h>
#include <math.h>

#define BATCH 8
#define CH    192
#define WW    56
#define NPTS  3136
#define C2    384
#define CG    96
#define MT    16
#define MSPLIT 4
#define LK    12
#define NCAND (MSPLIT*LK)
#define NREF  16

typedef float f32x4 __attribute__((ext_vector_type(4)));
typedef short bf16x8 __attribute__((ext_vector_type(8)));

__device__ __forceinline__ float gelu_exact(float v) {
  return 0.5f * v * (1.0f + erff(v * 0.7071067811865475f));
}
__device__ __forceinline__ unsigned short f2bf(float f) {
  unsigned int u = __float_as_uint(f);
  u = u + 0x7fffu + ((u >> 16) & 1u);
  return (unsigned short)(u >> 16);
}
__device__ __forceinline__ float bf2f(unsigned short h) {
  return __uint_as_float(((unsigned int)h) << 16);
}
__device__ __forceinline__ void gl_lds16(const void* g, void* lds) {
  __builtin_amdgcn_global_load_lds(
      (const __attribute__((address_space(1))) unsigned int*)g,
      (__attribute__((address_space(3))) unsigned int*)lds, 16, 0, 0);
}

// ---------------- K0: fold BN into weights, build scaled cos-table ----------------
__global__ void prep_kernel(
    const float* __restrict__ fc1_w, const float* __restrict__ fc1_b,
    const float* __restrict__ bn1_g, const float* __restrict__ bn1_b,
    const float* __restrict__ bn1_m, const float* __restrict__ bn1_v,
    const float* __restrict__ gc_w,  const float* __restrict__ gc_b,
    const float* __restrict__ bng_g, const float* __restrict__ bng_b,
    const float* __restrict__ bng_m, const float* __restrict__ bng_v,
    const float* __restrict__ fc2_w, const float* __restrict__ fc2_b,
    const float* __restrict__ bn2_g, const float* __restrict__ bn2_b,
    const float* __restrict__ bn2_m, const float* __restrict__ bn2_v,
    float* __restrict__ w1, float* __restrict__ b1,
    float* __restrict__ wg, float* __restrict__ bg,
    float* __restrict__ w2, float* __restrict__ b2,
    float* __restrict__ ftab)
{
  int i = blockIdx.x * 256 + threadIdx.x;
  if (i < 36864) {
    int d = i / CH;
    float s = bn1_g[d] / sqrtf(bn1_v[d] + 1e-5f);
    w1[i] = fc1_w[i] * s;
  } else if (i < 37056) {
    int d = i - 36864;
    float s = bn1_g[d] / sqrtf(bn1_v[d] + 1e-5f);
    b1[d] = (fc1_b[d] - bn1_m[d]) * s + bn1_b[d];
  } else if (i < 73920) {
    int j = i - 37056;
    int o = j / CG;
    float s = bng_g[o] / sqrtf(bng_v[o] + 1e-5f);
    wg[j] = gc_w[j] * s;
  } else if (i < 74304) {
    int o = i - 73920;
    float s = bng_g[o] / sqrtf(bng_v[o] + 1e-5f);
    bg[o] = (gc_b[o] - bng_m[o]) * s + bng_b[o];
  } else if (i < 148032) {
    int j = i - 74304;
    int d = j / C2;
    float s = bn2_g[d] / sqrtf(bn2_v[d] + 1e-5f);
    w2[j] = fc2_w[j] * s;
  } else if (i < 148224) {
    int d = i - 148032;
    float s = bn2_g[d] / sqrtf(bn2_v[d] + 1e-5f);
    b2[d] = (fc2_b[d] - bn2_m[d]) * s + bn2_b[d];
  } else if (i < 148280) {
    int delta = i - 148224;
    float s = 0.f;
    for (int t = 0; t < 48; ++t) {
      float omega = powf(10000.f, -(float)t / 48.f);
      s += cosf((float)delta * omega);
    }
    ftab[delta] = s * (-2.0f / (float)CH);   // pre-scaled: rel = ft[dy]+ft[dx]
  }
}

// ---------------- K1: h = BN1(fc1(x^T)) ; h layout [b][n][c] ----------------
__global__ __launch_bounds__(256) void fc1_kernel(
    const float* __restrict__ x, const float* __restrict__ w1,
    const float* __restrict__ b1, float* __restrict__ h)
{
  __shared__ float As[64*68];
  __shared__ float Bs[64*68];
  const int tid = threadIdx.x;
  const int ntile = blockIdx.x, dt = blockIdx.y, b = blockIdx.z;
  const int n0 = ntile * 64, d0 = dt * 64;
  const int ty = tid >> 4, tx = tid & 15;
  const float* xb = x + (size_t)b * CH * NPTS;
  float acc[4][4] = {};
  for (int k0 = 0; k0 < CH; k0 += 64) {
    if (k0) __syncthreads();
#pragma unroll
    for (int p = 0; p < 16; ++p) {
      int e = p * 256 + tid;
      int kk = e >> 6, r = e & 63;
      As[r*68 + kk] = xb[(size_t)(k0 + kk) * NPTS + n0 + r];
    }
#pragma unroll
    for (int p = 0; p < 4; ++p) {
      int e = p * 256 + tid;
      int dd = e >> 4, k4 = (e & 15) << 2;
      *(float4*)&Bs[dd*68 + k4] = *(const float4*)&w1[(size_t)(d0 + dd) * CH + k0 + k4];
    }
    __syncthreads();
#pragma unroll
    for (int kq = 0; kq < 16; ++kq) {
      float4 av[4], bv[4];
#pragma unroll
      for (int i = 0; i < 4; ++i) av[i] = *(const float4*)&As[(ty*4+i)*68 + kq*4];
#pragma unroll
      for (int j = 0; j < 4; ++j) bv[j] = *(const float4*)&Bs[(tx*4+j)*68 + kq*4];
#pragma unroll
      for (int i = 0; i < 4; ++i)
#pragma unroll
        for (int j = 0; j < 4; ++j)
          acc[i][j] += av[i].x*bv[j].x + av[i].y*bv[j].y + av[i].z*bv[j].z + av[i].w*bv[j].w;
    }
  }
#pragma unroll
  for (int i = 0; i < 4; ++i) {
    int n = n0 + ty*4 + i;
    float4 v;
    v.x = acc[i][0] + b1[d0 + tx*4 + 0];
    v.y = acc[i][1] + b1[d0 + tx*4 + 1];
    v.z = acc[i][2] + b1[d0 + tx*4 + 2];
    v.w = acc[i][3] + b1[d0 + tx*4 + 3];
    *(float4*)&h[((size_t)b * NPTS + n) * CH + d0 + tx*4] = v;
  }
}

// ---------------- K2: xn (f32 + bf16 hi/lo split) + sq ----------------
__global__ __launch_bounds__(256) void norm_kernel(
    const float* __restrict__ h, float* __restrict__ xnf,
    unsigned short* __restrict__ xhi, unsigned short* __restrict__ xlo,
    float* __restrict__ sqv)
{
  const int lane = threadIdx.x & 63;
  const int row = blockIdx.x * 4 + (threadIdx.x >> 6);
  const float* hr = h + (size_t)row * CH;
  float v0 = hr[lane], v1 = hr[lane + 64], v2 = hr[lane + 128];
  float s = v0*v0 + v1*v1 + v2*v2;
#pragma unroll
  for (int o = 32; o > 0; o >>= 1) s += __shfl_xor(s, o);
  float inv = 1.0f / fmaxf(sqrtf(s), 1e-12f);
  float x0 = v0 * inv, x1 = v1 * inv, x2 = v2 * inv;
  size_t base = (size_t)row * CH;
  xnf[base + lane      ] = x0;
  xnf[base + lane + 64 ] = x1;
  xnf[base + lane + 128] = x2;
  unsigned short h0 = f2bf(x0), h1 = f2bf(x1), h2 = f2bf(x2);
  xhi[base + lane      ] = h0;
  xhi[base + lane + 64 ] = h1;
  xhi[base + lane + 128] = h2;
  xlo[base + lane      ] = f2bf(x0 - bf2f(h0));
  xlo[base + lane + 64 ] = f2bf(x1 - bf2f(h1));
  xlo[base + lane + 128] = f2bf(x2 - bf2f(h2));
  if (lane == 0) sqv[row] = s * inv * inv;
}

// ---------------- K3: MFMA coarse dist, per-lane register top-12 ----------------
// grid (49, 4, 8) = 1568 blocks (~6/CU). Block: 64 n x 784 m, MT=16 m-tiles.
// LDS 25 KB dbuf -> 6 blocks/CU LDS-wise; launch_bounds(256,5) caps VGPR at 102
// (live set ~85-95, no spill). 3 independent MFMA chains; ft[dy] hoisted per tile.
__global__ __launch_bounds__(256, 5) void topk_kernel(
    const unsigned short* __restrict__ xhi, const unsigned short* __restrict__ xlo,
    const float* __restrict__ fts_g,
    float* __restrict__ pd, int* __restrict__ pi)
{
  __shared__ __align__(16) char LDSbuf[2 * 12288];   // [buf][hi 6144 | lo 6144]
  __shared__ float ft[64];

  const int tid  = threadIdx.x;
  const int lane = tid & 63;
  const int w    = tid >> 6;
  const int nt = blockIdx.x, ms = blockIdx.y, b = blockIdx.z;
  const int n0 = nt * 64;
  const size_t rowbase = (size_t)b * NPTS;

  if (tid < 64) ft[tid] = (tid < 56) ? fts_g[tid] : 0.0f;

  const int ar = lane & 15;
  const int hi = lane >> 4;
  const int ak = hi * 8;

  // B fragments (n-side) in registers
  const int n_b = n0 + w * 16 + ar;
  bf16x8 bhi[6], blo[6];
  {
    const unsigned short* pbh = xhi + (rowbase + n_b) * CH + ak;
    const unsigned short* pbl = xlo + (rowbase + n_b) * CH + ak;
#pragma unroll
    for (int c = 0; c < 6; ++c) {
      bhi[c] = *(const bf16x8*)(pbh + c * 32);
      blo[c] = *(const bf16x8*)(pbl + c * 32);
    }
  }
  const int yn_l = n_b / WW, xn_l = n_b % WW;

  float ld[LK]; int li[LK];
#pragma unroll
  for (int k = 0; k < LK; ++k) { ld[k] = INFINITY; li[k] = 0x7fffffff; }

  // DMA source offsets (per lane, constant across tiles): 3 chunks of 16B.
  // LDS linear slot L (within 6144B array) <- global byte r*384 + (off^swz(r)).
  int srcb[3];
#pragma unroll
  for (int j = 0; j < 3; ++j) {
    int L = (w & 1) * 3072 + j * 1024 + lane * 16;
    int r = L / 384, off = L % 384;
    srcb[j] = r * 384 + (off ^ ((r & 7) << 4));
  }
  const int ldsb = (w >= 2 ? 6144 : 0) + (w & 1) * 3072;   // wave-uniform dest base

  const int mbase = ms * (NPTS / MSPLIT);     // ms * 784 (= ms*14*56)
  const char* gb = (w < 2 ? (const char*)xhi : (const char*)xlo)
                   + (rowbase + mbase) * (CH * 2);

#define STAGE(BUF) do {                                                     \
  _Pragma("unroll")                                                         \
  for (int j = 0; j < 3; ++j)                                               \
    gl_lds16(gb + srcb[j], LDSbuf + (BUF) * 12288 + ldsb + j * 1024);       \
} while (0)

  STAGE(0);
  gb += 6144;

  int ym0 = ms * 14, xm0 = 0;

  for (int tt = 0; tt < 49; ++tt) {
    __syncthreads();                     // buf[tt&1] staged (vmcnt drained); prior reads done
    if (tt + 1 < 49) { STAGE((tt + 1) & 1); gb += 6144; }

    const int m0 = mbase + tt * MT;
    const int bufb = (tt & 1) * 12288;
    const int swz = (ar & 7) << 4;
    // 3 independent accumulator chains (order change is coarse-only; refine is exact)
    f32x4 a_hh = {}, a_hl = {}, a_lh = {};
#pragma unroll
    for (int c = 0; c < 6; ++c) {
      int off = bufb + ar * 384 + ((c * 64 + hi * 16) ^ swz);
      bf16x8 ah = *(const bf16x8*)(LDSbuf + off);
      bf16x8 al = *(const bf16x8*)(LDSbuf + off + 6144);
      a_hh = __builtin_amdgcn_mfma_f32_16x16x32_bf16(ah, bhi[c], a_hh, 0, 0, 0);
      a_hl = __builtin_amdgcn_mfma_f32_16x16x32_bf16(ah, blo[c], a_hl, 0, 0, 0);
      a_lh = __builtin_amdgcn_mfma_f32_16x16x32_bf16(al, bhi[c], a_lh, 0, 0, 0);
    }
    f32x4 s4;
#pragma unroll
    for (int i = 0; i < 4; ++i) s4[i] = a_hh[i] + (a_hl[i] + a_lh[i]);

    // epilogue: 4 values per lane, m = m0 + hi*4 + i; ym in {ym0, ym0+1}
    const float fdy0 = ft[abs(yn_l - ym0)];
    const float fdy1 = ft[abs(yn_l - ym0 - 1)];
#pragma unroll
    for (int i = 0; i < 4; ++i) {
      const int off_m = hi * 4 + i;
      int xm = xm0 + off_m;
      const bool wrap = (xm >= WW);
      if (wrap) xm -= WW;
      int dx = xn_l - xm; dx = dx < 0 ? -dx : dx;
      float d_ = (wrap ? fdy1 : fdy0) + ft[dx] - 2.0f * s4[i];
      if (d_ < ld[LK-1]) {
        float cd = d_; int ci = m0 + off_m;
#pragma unroll
        for (int s = 0; s < LK; ++s) {
          if (cd < ld[s]) { float t0=ld[s]; int t1=li[s]; ld[s]=cd; li[s]=ci; cd=t0; ci=t1; }
        }
      }
    }
    xm0 += MT;
    if (xm0 >= WW) { xm0 -= WW; ym0 += 1; }
  }

  // tail: 4-way merge per n (hi-lanes 0..3), write top-12 per (n, ms)
  __syncthreads();
  float* Md = (float*)LDSbuf;                 // 256*12*4 = 12288 B
  int*   Mi = (int*)(LDSbuf + 12288);
#pragma unroll
  for (int k = 0; k < LK; ++k) { Md[tid * LK + k] = ld[k]; Mi[tid * LK + k] = li[k]; }
  __syncthreads();
  if (tid < 64) {
    const int wv = tid >> 4, arr = tid & 15;
    const int n = n0 + tid;
    int lb[4];
#pragma unroll
    for (int hq = 0; hq < 4; ++hq) lb[hq] = (wv * 64 + hq * 16 + arr) * LK;
    int p0 = 0, p1 = 0, p2 = 0, p3 = 0;
    float* od = pd + ((rowbase + n) * MSPLIT + ms) * LK;
    int*   oi = pi + ((rowbase + n) * MSPLIT + ms) * LK;
    for (int k = 0; k < LK; ++k) {
      float bd = Md[lb[0] + p0]; int bi = Mi[lb[0] + p0]; int bq = 0;
      float dv = Md[lb[1] + p1]; int iv = Mi[lb[1] + p1];
      if (dv < bd || (dv == bd && iv < bi)) { bd = dv; bi = iv; bq = 1; }
      dv = Md[lb[2] + p2]; iv = Mi[lb[2] + p2];
      if (dv < bd || (dv == bd && iv < bi)) { bd = dv; bi = iv; bq = 2; }
      dv = Md[lb[3] + p3]; iv = Mi[lb[3] + p3];
      if (dv < bd || (dv == bd && iv < bi)) { bd = dv; bi = iv; bq = 3; }
      if (bq == 0) { if (p0 < LK-1) ++p0; else Md[lb[0]+p0] = INFINITY; }
      else if (bq == 1) { if (p1 < LK-1) ++p1; else Md[lb[1]+p1] = INFINITY; }
      else if (bq == 2) { if (p2 < LK-1) ++p2; else Md[lb[2]+p2] = INFINITY; }
      else              { if (p3 < LK-1) ++p3; else Md[lb[3]+p3] = INFINITY; }
      od[k] = bd; oi[k] = bi;
    }
  }
#undef STAGE
}

// ---------------- K3b: pool 48 coarse candidates -> exact f32 refine -> top-9 ----------------
__global__ __launch_bounds__(256) void refine_kernel(
    const float* __restrict__ pd, const int* __restrict__ pi,
    const float* __restrict__ xn, const float* __restrict__ sqv,
    const float* __restrict__ fts_g, int* __restrict__ nn)
{
  __shared__ float alld[4][NCAND];
  __shared__ int   alli[4][NCAND];
  __shared__ int   ci_s[4][NREF];
  __shared__ float ft[56];
  const int tid = threadIdx.x;
  const int w = tid >> 6, lane = tid & 63;
  if (tid < 56) ft[tid] = fts_g[tid];
  const int row = blockIdx.x * 4 + w;
  const int b = row / NPTS;
  const int n_loc = row - b * NPTS;

  if (lane < NCAND) {
    alld[w][lane] = pd[(size_t)row * NCAND + lane];
    alli[w][lane] = pi[(size_t)row * NCAND + lane];
  }
  __syncthreads();
  if (lane < NCAND) {
    float d0 = alld[w][lane]; int i0 = alli[w][lane];
    int rank = 0;
    for (int j = 0; j < NCAND; ++j) {
      float dj = alld[w][j]; int ij = alli[w][j];
      rank += (dj < d0 || (dj == d0 && ij < i0)) ? 1 : 0;
    }
    if (rank < NREF) ci_s[w][rank] = i0;
  }
  __syncthreads();

  const float* xrow = xn + (size_t)row * CH;
  float a0 = xrow[lane], a1 = xrow[lane + 64], a2 = xrow[lane + 128];
  const int yn_ = n_loc / WW, xq_ = n_loc % WW;
  const size_t xbase = (size_t)b * NPTS * CH;
  float myd = INFINITY; int myi = 0x7fffffff;
#pragma unroll 4
  for (int c = 0; c < NREF; ++c) {
    int m = ci_s[w][c];
    const float* xm = xn + xbase + (size_t)m * CH;
    float s = a0 * xm[lane] + a1 * xm[lane + 64] + a2 * xm[lane + 128];
#pragma unroll
    for (int o = 32; o > 0; o >>= 1) s += __shfl_xor(s, o);
    if (lane == c) {
      int ym = m / WW, xm_ = m % WW;
      int dy = yn_ - ym; dy = dy < 0 ? -dy : dy;
      int dx = xq_ - xm_; dx = dx < 0 ? -dx : dx;
      myd = sqv[(size_t)b * NPTS + m] - 2.0f * s + (ft[dy] + ft[dx]);
      myi = m;
    }
  }
  if (lane < NREF) {
    int rank = 0;
    for (int j = 0; j < NREF; ++j) {
      float dj = __shfl(myd, j); int ij = __shfl(myi, j);
      rank += (dj < myd || (dj == myd && ij < myi)) ? 1 : 0;
    }
    if (rank < 9) nn[(size_t)row * 9 + rank] = myi;
  }
}

// ---------------- K3c: edge features d = max_j(x_j) - h, once ----------------
__global__ __launch_bounds__(256) void edge_kernel(
    const float* __restrict__ h, const int* __restrict__ nn,
    float* __restrict__ df)
{
  __shared__ int nns[576];
  const int n0g = blockIdx.x * 64;
  const int b = n0g / NPTS;
  const size_t rowbase = (size_t)b * NPTS;
  const int tid = threadIdx.x;
  for (int e = tid; e < 576; e += 256)
    nns[e] = nn[(size_t)(n0g + e / 9) * 9 + (e % 9)];
  __syncthreads();
#pragma unroll
  for (int p = 0; p < 12; ++p) {
    int e = tid + 256 * p;
    int r = e / 48, c4 = (e % 48) * 4;
    float4 hv = *(const float4*)&h[(size_t)(n0g + r) * CH + c4];
    float4 mx = make_float4(-INFINITY, -INFINITY, -INFINITY, -INFINITY);
#pragma unroll
    for (int k = 0; k < 9; ++k) {
      float4 nv = *(const float4*)&h[(rowbase + nns[r*9 + k]) * CH + c4];
      mx.x = fmaxf(mx.x, nv.x); mx.y = fmaxf(mx.y, nv.y);
      mx.z = fmaxf(mx.z, nv.z); mx.w = fmaxf(mx.w, nv.w);
    }
    float4 ov;
    ov.x = mx.x - hv.x; ov.y = mx.y - hv.y; ov.z = mx.z - hv.z; ov.w = mx.w - hv.w;
    *(float4*)&df[(size_t)(n0g + r) * CH + c4] = ov;
  }
}

// ---------------- K4: grouped GEMM + GELU (no gathers), y in bf16 ----------------
__global__ __launch_bounds__(256) void gc_kernel(
    const float* __restrict__ h, const float* __restrict__ df,
    const float* __restrict__ wg, const float* __restrict__ bg,
    unsigned short* __restrict__ y)
{
  __shared__ float Gs[64][52];
  __shared__ float Ws[48][52];
  const int tid = threadIdx.x;
  const int rt = blockIdx.x, ct = blockIdx.y;
  const int n0g = rt * 64;
  const int g = ct >> 1;
  const int dd0 = ct * 48;
  const float* src = (g < 2) ? h : df;
  const int cb = (g & 1) * CG;
  const int ty = tid >> 4, tx = tid & 15;
  float acc[4][3] = {};
  for (int k0 = 0; k0 < CG; k0 += 48) {
    __syncthreads();
#pragma unroll
    for (int p = 0; p < 3; ++p) {
      int e = tid + p * 256;
      int r = e / 12, c4 = (e % 12) * 4;
      *(float4*)&Gs[r][c4] = *(const float4*)&src[(size_t)(n0g + r) * CH + cb + k0 + c4];
    }
    for (int e = tid; e < 2304; e += 256) {
      int dd = e / 48, kk = e % 48;
      Ws[dd][kk] = wg[(size_t)(dd0 + dd) * CG + k0 + kk];
    }
    __syncthreads();
#pragma unroll
    for (int kq = 0; kq < 12; ++kq) {
      float4 av[4], bv[3];
#pragma unroll
      for (int i = 0; i < 4; ++i) av[i] = *(const float4*)&Gs[ty*4 + i][kq*4];
#pragma unroll
      for (int j = 0; j < 3; ++j) bv[j] = *(const float4*)&Ws[tx*3 + j][kq*4];
#pragma unroll
      for (int i = 0; i < 4; ++i)
#pragma unroll
        for (int j = 0; j < 3; ++j)
          acc[i][j] += av[i].x*bv[j].x + av[i].y*bv[j].y + av[i].z*bv[j].z + av[i].w*bv[j].w;
    }
  }
#pragma unroll
  for (int i = 0; i < 4; ++i) {
    int row = n0g + ty*4 + i;
#pragma unroll
    for (int j = 0; j < 3; ++j) {
      int oc = dd0 + tx*3 + j;
      float v = acc[i][j] + bg[oc];
      y[(size_t)row * C2 + oc] = f2bf(gelu_exact(v));
    }
  }
}

// ---------------- K5: fc2 + BN2 + residual (bf16 y input) ----------------
__global__ __launch_bounds__(256) void fc2_kernel(
    const unsigned short* __restrict__ yv, const float* __restrict__ w2,
    const float* __restrict__ b2, const float* __restrict__ x, float* __restrict__ out)
{
  __shared__ float As[64*68];
  __shared__ float Bs[64*68];
  __shared__ float Os[64*68];
  const int tid = threadIdx.x;
  const int rt = blockIdx.x, dt = blockIdx.y;
  const int n0g = rt * 64;
  const int b = n0g / NPTS;
  const int nloc0 = n0g - b * NPTS;
  const int d0 = dt * 64;
  const int ty = tid >> 4, tx = tid & 15;
  float acc[4][4] = {};
  for (int k0 = 0; k0 < C2; k0 += 64) {
    if (k0) __syncthreads();
#pragma unroll
    for (int p = 0; p < 2; ++p) {
      int e = p * 256 + tid;
      int r = e >> 3, k8 = (e & 7) * 8;
      uint4 v = *(const uint4*)&yv[(size_t)(n0g + r) * C2 + k0 + k8];
      const unsigned short* u = (const unsigned short*)&v;
#pragma unroll
      for (int j = 0; j < 8; ++j) As[r*68 + k8 + j] = bf2f(u[j]);
    }
#pragma unroll
    for (int p = 0; p < 4; ++p) {
      int e = p * 256 + tid;
      int dd = e >> 4, k4 = (e & 15) << 2;
      *(float4*)&Bs[dd*68 + k4] = *(const float4*)&w2[(size_t)(d0 + dd) * C2 + k0 + k4];
    }
    __syncthreads();
#pragma unroll
    for (int kq = 0; kq < 16; ++kq) {
      float4 av[4], bv[4];
#pragma unroll
      for (int i = 0; i < 4; ++i) av[i] = *(const float4*)&As[(ty*4+i)*68 + kq*4];
#pragma unroll
      for (int j = 0; j < 4; ++j) bv[j] = *(const float4*)&Bs[(tx*4+j)*68 + kq*4];
#pragma unroll
      for (int i = 0; i < 4; ++i)
#pragma unroll
        for (int j = 0; j < 4; ++j)
          acc[i][j] += av[i].x*bv[j].x + av[i].y*bv[j].y + av[i].z*bv[j].z + av[i].w*bv[j].w;
    }
  }
  __syncthreads();
#pragma unroll
  for (int i = 0; i < 4; ++i)
#pragma unroll
    for (int j = 0; j < 4; ++j)
      Os[(tx*4 + j)*68 + ty*4 + i] = acc[i][j];
  __syncthreads();
#pragma unroll
  for (int p = 0; p < 4; ++p) {
    int cl = (tid >> 4) + p * 16;
    int n4 = (tid & 15) << 2;
    float4 v = *(const float4*)&Os[cl*68 + n4];
    size_t gi = ((size_t)b * CH + d0 + cl) * NPTS + nloc0 + n4;
    float bb = b2[d0 + cl];
    float4 xr = *(const float4*)&x[gi];
    v.x += bb + xr.x; v.y += bb + xr.y; v.z += bb + xr.z; v.w += bb + xr.w;
    *(float4*)&out[gi] = v;
  }
}

extern "C" void kernel_launch(void* const* d_in, const int* in_sizes, int n_in,
                              void* d_out, int out_size, void* d_ws, size_t ws_size,
                              hipStream_t stream) {
  const float* x     = (const float*)d_in[0];
  const float* fc1_w = (const float*)d_in[1];
  const float* fc1_b = (const float*)d_in[2];
  const float* bn1_g = (const float*)d_in[3];
  const float* bn1_b = (const float*)d_in[4];
  const float* bn1_m = (const float*)d_in[5];
  const float* bn1_v = (const float*)d_in[6];
  const float* gc_w  = (const float*)d_in[7];
  const float* gc_b  = (const float*)d_in[8];
  const float* bng_g = (const float*)d_in[9];
  const float* bng_b = (const float*)d_in[10];
  const float* bng_m = (const float*)d_in[11];
  const float* bng_v = (const float*)d_in[12];
  const float* fc2_w = (const float*)d_in[13];
  const float* fc2_b = (const float*)d_in[14];
  const float* bn2_g = (const float*)d_in[15];
  const float* bn2_b = (const float*)d_in[16];
  const float* bn2_m = (const float*)d_in[17];
  const float* bn2_v = (const float*)d_in[18];

  float* ws = (float*)d_ws;
  size_t o = 0;
  float* W1 = ws + o; o += 36864;
  float* B1 = ws + o; o += 192;
  float* WG = ws + o; o += 36864;
  float* BG = ws + o; o += 384;
  float* W2 = ws + o; o += 73728;
  float* B2 = ws + o; o += 192;
  float* FT = ws + o; o += 64;
  float* H  = ws + o; o += (size_t)25088 * 192;     // 4,816,896 f32
  float* SQ = ws + o; o += 25088;
  int*   NN = (int*)(ws + o); o += 25088 * 9;
  float* SCR = ws + o;
  unsigned short* XHI = (unsigned short*)SCR;                    // 4,816,896 u16
  unsigned short* XLO = XHI + (size_t)25088 * 192;               // 4,816,896 u16
  float* DF  = SCR;                                              // overlays XHI+XLO (exact fit)
  float* XN  = SCR + (size_t)4816896;                            // 4,816,896 f32
  unsigned short* YB = (unsigned short*)XN;                      // overlays XN (exact fit)
  float* PD  = XN + (size_t)4816896;                             // 25088*48 f32
  int*   PI  = (int*)(PD + (size_t)25088 * NCAND);               // 25088*48 int
  (void)ws_size; (void)in_sizes; (void)n_in; (void)out_size;

  hipLaunchKernelGGL(prep_kernel, dim3(580), dim3(256), 0, stream,
                     fc1_w, fc1_b, bn1_g, bn1_b, bn1_m, bn1_v,
                     gc_w, gc_b, bng_g, bng_b, bng_m, bng_v,
                     fc2_w, fc2_b, bn2_g, bn2_b, bn2_m, bn2_v,
                     W1, B1, WG, BG, W2, B2, FT);
  hipLaunchKernelGGL(fc1_kernel, dim3(49, 3, 8), dim3(256), 0, stream, x, W1, B1, H);
  hipLaunchKernelGGL(norm_kernel, dim3(6272), dim3(256), 0, stream, H, XN, XHI, XLO, SQ);
  hipLaunchKernelGGL(topk_kernel, dim3(49, MSPLIT, 8), dim3(256), 0, stream, XHI, XLO, FT, PD, PI);
  hipLaunchKernelGGL(refine_kernel, dim3(6272), dim3(256), 0, stream, PD, PI, XN, SQ, FT, NN);
  hipLaunchKernelGGL(edge_kernel, dim3(392), dim3(256), 0, stream, H, NN, DF);
  hipLaunchKernelGGL(gc_kernel, dim3(392, 8), dim3(256), 0, stream, H, DF, WG, BG, YB);
  hipLaunchKernelGGL(fc2_kernel, dim3(392, 3), dim3(256), 0, stream, YB, W2, B2, x, (float*)d_out);
}

// Round 7
// 654.132 us; speedup vs baseline: 5.3892x; 1.8814x over previous
//
#include <hip/hip_runtime.h>
#include <math.h>

#define BATCH 8
#define CH    192
#define WW    56
#define NPTS  3136
#define C2    384
#define CG    96
#define MT    16
#define MSPLIT 4
#define LK    12
#define NCAND (MSPLIT*LK)
#define NREF  16
#define MQ    (NPTS/MSPLIT)   // 784 rows per m-quarter

typedef float f32x4 __attribute__((ext_vector_type(4)));
typedef short bf16x8 __attribute__((ext_vector_type(8)));

__device__ __forceinline__ float gelu_exact(float v) {
  return 0.5f * v * (1.0f + erff(v * 0.7071067811865475f));
}
__device__ __forceinline__ unsigned short f2bf(float f) {
  unsigned int u = __float_as_uint(f);
  u = u + 0x7fffu + ((u >> 16) & 1u);
  return (unsigned short)(u >> 16);
}
__device__ __forceinline__ float bf2f(unsigned short h) {
  return __uint_as_float(((unsigned int)h) << 16);
}
__device__ __forceinline__ void gl_lds16(const void* g, void* lds) {
  __builtin_amdgcn_global_load_lds(
      (const __attribute__((address_space(1))) unsigned int*)g,
      (__attribute__((address_space(3))) unsigned int*)lds, 16, 0, 0);
}
// order-preserving f32 -> u32 (ascending)
__device__ __forceinline__ unsigned fmono(float f) {
  unsigned u = __float_as_uint(f);
  return u ^ ((unsigned)((int)u >> 31) | 0x80000000u);
}

// ---------------- K0: fold BN into weights, build scaled cos-table ----------------
__global__ void prep_kernel(
    const float* __restrict__ fc1_w, const float* __restrict__ fc1_b,
    const float* __restrict__ bn1_g, const float* __restrict__ bn1_b,
    const float* __restrict__ bn1_m, const float* __restrict__ bn1_v,
    const float* __restrict__ gc_w,  const float* __restrict__ gc_b,
    const float* __restrict__ bng_g, const float* __restrict__ bng_b,
    const float* __restrict__ bng_m, const float* __restrict__ bng_v,
    const float* __restrict__ fc2_w, const float* __restrict__ fc2_b,
    const float* __restrict__ bn2_g, const float* __restrict__ bn2_b,
    const float* __restrict__ bn2_m, const float* __restrict__ bn2_v,
    float* __restrict__ w1, float* __restrict__ b1,
    float* __restrict__ wg, float* __restrict__ bg,
    float* __restrict__ w2, float* __restrict__ b2,
    float* __restrict__ ftab)
{
  int i = blockIdx.x * 256 + threadIdx.x;
  if (i < 36864) {
    int d = i / CH;
    float s = bn1_g[d] / sqrtf(bn1_v[d] + 1e-5f);
    w1[i] = fc1_w[i] * s;
  } else if (i < 37056) {
    int d = i - 36864;
    float s = bn1_g[d] / sqrtf(bn1_v[d] + 1e-5f);
    b1[d] = (fc1_b[d] - bn1_m[d]) * s + bn1_b[d];
  } else if (i < 73920) {
    int j = i - 37056;
    int o = j / CG;
    float s = bng_g[o] / sqrtf(bng_v[o] + 1e-5f);
    wg[j] = gc_w[j] * s;
  } else if (i < 74304) {
    int o = i - 73920;
    float s = bng_g[o] / sqrtf(bng_v[o] + 1e-5f);
    bg[o] = (gc_b[o] - bng_m[o]) * s + bng_b[o];
  } else if (i < 148032) {
    int j = i - 74304;
    int d = j / C2;
    float s = bn2_g[d] / sqrtf(bn2_v[d] + 1e-5f);
    w2[j] = fc2_w[j] * s;
  } else if (i < 148224) {
    int d = i - 148032;
    float s = bn2_g[d] / sqrtf(bn2_v[d] + 1e-5f);
    b2[d] = (fc2_b[d] - bn2_m[d]) * s + bn2_b[d];
  } else if (i < 148280) {
    int delta = i - 148224;
    float s = 0.f;
    for (int t = 0; t < 48; ++t) {
      float omega = powf(10000.f, -(float)t / 48.f);
      s += cosf((float)delta * omega);
    }
    ftab[delta] = s * (-2.0f / (float)CH);   // pre-scaled: rel = ft[dy]+ft[dx]
  }
}

// ---------------- K1: h = BN1(fc1(x^T)) ; h layout [b][n][c] ----------------
__global__ __launch_bounds__(256) void fc1_kernel(
    const float* __restrict__ x, const float* __restrict__ w1,
    const float* __restrict__ b1, float* __restrict__ h)
{
  __shared__ float As[64*68];
  __shared__ float Bs[64*68];
  const int tid = threadIdx.x;
  const int ntile = blockIdx.x, dt = blockIdx.y, b = blockIdx.z;
  const int n0 = ntile * 64, d0 = dt * 64;
  const int ty = tid >> 4, tx = tid & 15;
  const float* xb = x + (size_t)b * CH * NPTS;
  float acc[4][4] = {};
  for (int k0 = 0; k0 < CH; k0 += 64) {
    if (k0) __syncthreads();
#pragma unroll
    for (int p = 0; p < 16; ++p) {
      int e = p * 256 + tid;
      int kk = e >> 6, r = e & 63;
      As[r*68 + kk] = xb[(size_t)(k0 + kk) * NPTS + n0 + r];
    }
#pragma unroll
    for (int p = 0; p < 4; ++p) {
      int e = p * 256 + tid;
      int dd = e >> 4, k4 = (e & 15) << 2;
      *(float4*)&Bs[dd*68 + k4] = *(const float4*)&w1[(size_t)(d0 + dd) * CH + k0 + k4];
    }
    __syncthreads();
#pragma unroll
    for (int kq = 0; kq < 16; ++kq) {
      float4 av[4], bv[4];
#pragma unroll
      for (int i = 0; i < 4; ++i) av[i] = *(const float4*)&As[(ty*4+i)*68 + kq*4];
#pragma unroll
      for (int j = 0; j < 4; ++j) bv[j] = *(const float4*)&Bs[(tx*4+j)*68 + kq*4];
#pragma unroll
      for (int i = 0; i < 4; ++i)
#pragma unroll
        for (int j = 0; j < 4; ++j)
          acc[i][j] += av[i].x*bv[j].x + av[i].y*bv[j].y + av[i].z*bv[j].z + av[i].w*bv[j].w;
    }
  }
#pragma unroll
  for (int i = 0; i < 4; ++i) {
    int n = n0 + ty*4 + i;
    float4 v;
    v.x = acc[i][0] + b1[d0 + tx*4 + 0];
    v.y = acc[i][1] + b1[d0 + tx*4 + 1];
    v.z = acc[i][2] + b1[d0 + tx*4 + 2];
    v.w = acc[i][3] + b1[d0 + tx*4 + 3];
    *(float4*)&h[((size_t)b * NPTS + n) * CH + d0 + tx*4] = v;
  }
}

// ---------------- K2: xn (f32 + bf16 hi/lo split) + sq ----------------
__global__ __launch_bounds__(256) void norm_kernel(
    const float* __restrict__ h, float* __restrict__ xnf,
    unsigned short* __restrict__ xhi, unsigned short* __restrict__ xlo,
    float* __restrict__ sqv)
{
  const int lane = threadIdx.x & 63;
  const int row = blockIdx.x * 4 + (threadIdx.x >> 6);
  const float* hr = h + (size_t)row * CH;
  float v0 = hr[lane], v1 = hr[lane + 64], v2 = hr[lane + 128];
  float s = v0*v0 + v1*v1 + v2*v2;
#pragma unroll
  for (int o = 32; o > 0; o >>= 1) s += __shfl_xor(s, o);
  float inv = 1.0f / fmaxf(sqrtf(s), 1e-12f);
  float x0 = v0 * inv, x1 = v1 * inv, x2 = v2 * inv;
  size_t base = (size_t)row * CH;
  xnf[base + lane      ] = x0;
  xnf[base + lane + 64 ] = x1;
  xnf[base + lane + 128] = x2;
  unsigned short h0 = f2bf(x0), h1 = f2bf(x1), h2 = f2bf(x2);
  xhi[base + lane      ] = h0;
  xhi[base + lane + 64 ] = h1;
  xhi[base + lane + 128] = h2;
  xlo[base + lane      ] = f2bf(x0 - bf2f(h0));
  xlo[base + lane + 64 ] = f2bf(x1 - bf2f(h1));
  xlo[base + lane + 128] = f2bf(x2 - bf2f(h2));
  if (lane == 0) sqv[row] = s * inv * inv;
}

// ---------------- K3: MFMA coarse dist, per-lane packed-key top-12 ----------------
// grid 1568 (1D). XCD swizzle: b = bid%8 (one batch per XCD -> L2 holds its
// m-quarters, kills round-6's 1.49 GB thrash), ms/nt from bid>>3.
// Packed key = (mono(dist) & ~1023) | local_m  -> 12 regs/list, min/max insert.
__global__ __launch_bounds__(256, 4) void topk_kernel(
    const unsigned short* __restrict__ xhi, const unsigned short* __restrict__ xlo,
    const float* __restrict__ fts_g,
    unsigned* __restrict__ pd)
{
  __shared__ __align__(16) char LDSbuf[2 * 12288];   // [buf][hi 6144 | lo 6144]
  __shared__ float ft[64];

  const int tid  = threadIdx.x;
  const int lane = tid & 63;
  const int w    = tid >> 6;
  const int bid  = blockIdx.x;
  const int b    = bid & 7;            // XCD-aligned (round-robin assumption)
  const int r_   = bid >> 3;
  const int ms   = r_ / 49;
  const int nt   = r_ % 49;
  const int n0 = nt * 64;
  const size_t rowbase = (size_t)b * NPTS;

  if (tid < 64) ft[tid] = (tid < 56) ? fts_g[tid] : 0.0f;

  const int ar = lane & 15;
  const int hi = lane >> 4;
  const int ak = hi * 8;

  // B fragments (n-side) in registers
  const int n_b = n0 + w * 16 + ar;
  bf16x8 bhi[6], blo[6];
  {
    const unsigned short* pbh = xhi + (rowbase + n_b) * CH + ak;
    const unsigned short* pbl = xlo + (rowbase + n_b) * CH + ak;
#pragma unroll
    for (int c = 0; c < 6; ++c) {
      bhi[c] = *(const bf16x8*)(pbh + c * 32);
      blo[c] = *(const bf16x8*)(pbl + c * 32);
    }
  }
  const int yn_l = n_b / WW, xn_l = n_b % WW;

  unsigned ld[LK];
#pragma unroll
  for (int k = 0; k < LK; ++k) ld[k] = 0xFFFFFFFFu;

  // DMA source offsets (per lane, constant across tiles): 3 chunks of 16B.
  int srcb[3];
#pragma unroll
  for (int j = 0; j < 3; ++j) {
    int L = (w & 1) * 3072 + j * 1024 + lane * 16;
    int r = L / 384, off = L % 384;
    srcb[j] = r * 384 + (off ^ ((r & 7) << 4));
  }
  const int ldsb = (w >= 2 ? 6144 : 0) + (w & 1) * 3072;   // wave-uniform dest base

  const int mbase = ms * MQ;
  const char* gb = (w < 2 ? (const char*)xhi : (const char*)xlo)
                   + (rowbase + mbase) * (CH * 2);

#define STAGE(BUF) do {                                                     \
  _Pragma("unroll")                                                         \
  for (int j = 0; j < 3; ++j)                                               \
    gl_lds16(gb + srcb[j], LDSbuf + (BUF) * 12288 + ldsb + j * 1024);       \
} while (0)

  STAGE(0);
  gb += 6144;

  int ym0 = ms * 14, xm0 = 0;

  for (int tt = 0; tt < 49; ++tt) {
    __syncthreads();                     // buf[tt&1] staged (vmcnt drained); prior reads done
    if (tt + 1 < 49) { STAGE((tt + 1) & 1); gb += 6144; }

    const int bufb = (tt & 1) * 12288;
    const int swz = (ar & 7) << 4;
    f32x4 a_hh = {}, a_hl = {}, a_lh = {};
#pragma unroll
    for (int c = 0; c < 6; ++c) {
      int off = bufb + ar * 384 + ((c * 64 + hi * 16) ^ swz);
      bf16x8 ah = *(const bf16x8*)(LDSbuf + off);
      bf16x8 al = *(const bf16x8*)(LDSbuf + off + 6144);
      a_hh = __builtin_amdgcn_mfma_f32_16x16x32_bf16(ah, bhi[c], a_hh, 0, 0, 0);
      a_hl = __builtin_amdgcn_mfma_f32_16x16x32_bf16(ah, blo[c], a_hl, 0, 0, 0);
      a_lh = __builtin_amdgcn_mfma_f32_16x16x32_bf16(al, bhi[c], a_lh, 0, 0, 0);
    }
    f32x4 s4;
#pragma unroll
    for (int i = 0; i < 4; ++i) s4[i] = a_hh[i] + (a_hl[i] + a_lh[i]);

    // epilogue: 4 values per lane, local m = tt*16 + hi*4 + i; ym in {ym0, ym0+1}
    const float fdy0 = ft[abs(yn_l - ym0)];
    const float fdy1 = ft[abs(yn_l - ym0 - 1)];
    const int locb = tt * MT + hi * 4;
#pragma unroll
    for (int i = 0; i < 4; ++i) {
      int xm = xm0 + hi * 4 + i;
      const bool wrap = (xm >= WW);
      if (wrap) xm -= WW;
      int dx = xn_l - xm; dx = dx < 0 ? -dx : dx;
      float d_ = (wrap ? fdy1 : fdy0) + ft[dx] - 2.0f * s4[i];
      unsigned key = (fmono(d_) & 0xFFFFFC00u) | (unsigned)(locb + i);
      if (key < ld[LK-1]) {
        unsigned cd = key;
#pragma unroll
        for (int s = 0; s < LK; ++s) {
          unsigned mn = ld[s] < cd ? ld[s] : cd;
          unsigned mx = ld[s] < cd ? cd : ld[s];
          ld[s] = mn; cd = mx;
        }
      }
    }
    xm0 += MT;
    if (xm0 >= WW) { xm0 -= WW; ym0 += 1; }
  }

  // tail: 4-way merge per n (hi-lanes 0..3), write top-12 keys per (n, ms)
  __syncthreads();
  unsigned* Md = (unsigned*)LDSbuf;           // 256*12*4 = 12288 B
#pragma unroll
  for (int k = 0; k < LK; ++k) Md[tid * LK + k] = ld[k];
  __syncthreads();
  if (tid < 64) {
    const int wv = tid >> 4, arr = tid & 15;
    const int n = n0 + tid;
    int lb[4];
#pragma unroll
    for (int hq = 0; hq < 4; ++hq) lb[hq] = (wv * 64 + hq * 16 + arr) * LK;
    int p0 = 0, p1 = 0, p2 = 0, p3 = 0;
    unsigned* od = pd + ((rowbase + n) * MSPLIT + ms) * LK;
    for (int k = 0; k < LK; ++k) {
      unsigned bk = Md[lb[0] + p0]; int bq = 0;
      unsigned v1 = Md[lb[1] + p1];
      if (v1 < bk) { bk = v1; bq = 1; }
      unsigned v2 = Md[lb[2] + p2];
      if (v2 < bk) { bk = v2; bq = 2; }
      unsigned v3 = Md[lb[3] + p3];
      if (v3 < bk) { bk = v3; bq = 3; }
      if (bq == 0) { if (p0 < LK-1) ++p0; else Md[lb[0]+p0] = 0xFFFFFFFFu; }
      else if (bq == 1) { if (p1 < LK-1) ++p1; else Md[lb[1]+p1] = 0xFFFFFFFFu; }
      else if (bq == 2) { if (p2 < LK-1) ++p2; else Md[lb[2]+p2] = 0xFFFFFFFFu; }
      else              { if (p3 < LK-1) ++p3; else Md[lb[3]+p3] = 0xFFFFFFFFu; }
      od[k] = bk;
    }
  }
#undef STAGE
}

// ---------------- K3b: pool 48 packed coarse keys -> exact f32 refine -> top-9 ----------------
__global__ __launch_bounds__(256) void refine_kernel(
    const unsigned* __restrict__ pd,
    const float* __restrict__ xn, const float* __restrict__ sqv,
    const float* __restrict__ fts_g, int* __restrict__ nn)
{
  __shared__ unsigned allk[4][NCAND];
  __shared__ int      ci_s[4][NREF];
  __shared__ float ft[56];
  const int tid = threadIdx.x;
  const int w = tid >> 6, lane = tid & 63;
  if (tid < 56) ft[tid] = fts_g[tid];
  const int row = blockIdx.x * 4 + w;
  const int b = row / NPTS;
  const int n_loc = row - b * NPTS;

  if (lane < NCAND) allk[w][lane] = pd[(size_t)row * NCAND + lane];
  __syncthreads();
  // rank-select coarse top-16 on packed keys; slot order = global-idx tie-break
  if (lane < NCAND) {
    unsigned k0 = allk[w][lane];
    int rank = 0;
    for (int j = 0; j < NCAND; ++j) {
      unsigned kj = allk[w][j];
      rank += (kj < k0 || (kj == k0 && j < lane)) ? 1 : 0;
    }
    if (rank < NREF) ci_s[w][rank] = (lane / LK) * MQ + (int)(k0 & 1023u);
  }
  __syncthreads();

  const float* xrow = xn + (size_t)row * CH;
  float a0 = xrow[lane], a1 = xrow[lane + 64], a2 = xrow[lane + 128];
  const int yn_ = n_loc / WW, xq_ = n_loc % WW;
  const size_t xbase = (size_t)b * NPTS * CH;
  float myd = INFINITY; int myi = 0x7fffffff;
#pragma unroll 4
  for (int c = 0; c < NREF; ++c) {
    int m = ci_s[w][c];
    const float* xm = xn + xbase + (size_t)m * CH;
    float s = a0 * xm[lane] + a1 * xm[lane + 64] + a2 * xm[lane + 128];
#pragma unroll
    for (int o = 32; o > 0; o >>= 1) s += __shfl_xor(s, o);
    if (lane == c) {
      int ym = m / WW, xm_ = m % WW;
      int dy = yn_ - ym; dy = dy < 0 ? -dy : dy;
      int dx = xq_ - xm_; dx = dx < 0 ? -dx : dx;
      myd = sqv[(size_t)b * NPTS + m] - 2.0f * s + (ft[dy] + ft[dx]);
      myi = m;
    }
  }
  if (lane < NREF) {
    int rank = 0;
    for (int j = 0; j < NREF; ++j) {
      float dj = __shfl(myd, j); int ij = __shfl(myi, j);
      rank += (dj < myd || (dj == myd && ij < myi)) ? 1 : 0;
    }
    if (rank < 9) nn[(size_t)row * 9 + rank] = myi;
  }
}

// ---------------- K3c: edge features d = max_j(x_j) - h, once ----------------
__global__ __launch_bounds__(256) void edge_kernel(
    const float* __restrict__ h, const int* __restrict__ nn,
    float* __restrict__ df)
{
  __shared__ int nns[576];
  const int n0g = blockIdx.x * 64;
  const int b = n0g / NPTS;
  const size_t rowbase = (size_t)b * NPTS;
  const int tid = threadIdx.x;
  for (int e = tid; e < 576; e += 256)
    nns[e] = nn[(size_t)(n0g + e / 9) * 9 + (e % 9)];
  __syncthreads();
#pragma unroll
  for (int p = 0; p < 12; ++p) {
    int e = tid + 256 * p;
    int r = e / 48, c4 = (e % 48) * 4;
    float4 hv = *(const float4*)&h[(size_t)(n0g + r) * CH + c4];
    float4 mx = make_float4(-INFINITY, -INFINITY, -INFINITY, -INFINITY);
#pragma unroll
    for (int k = 0; k < 9; ++k) {
      float4 nv = *(const float4*)&h[(rowbase + nns[r*9 + k]) * CH + c4];
      mx.x = fmaxf(mx.x, nv.x); mx.y = fmaxf(mx.y, nv.y);
      mx.z = fmaxf(mx.z, nv.z); mx.w = fmaxf(mx.w, nv.w);
    }
    float4 ov;
    ov.x = mx.x - hv.x; ov.y = mx.y - hv.y; ov.z = mx.z - hv.z; ov.w = mx.w - hv.w;
    *(float4*)&df[(size_t)(n0g + r) * CH + c4] = ov;
  }
}

// ---------------- K4: grouped GEMM + GELU (no gathers), y in bf16 ----------------
__global__ __launch_bounds__(256) void gc_kernel(
    const float* __restrict__ h, const float* __restrict__ df,
    const float* __restrict__ wg, const float* __restrict__ bg,
    unsigned short* __restrict__ y)
{
  __shared__ float Gs[64][52];
  __shared__ float Ws[48][52];
  const int tid = threadIdx.x;
  const int rt = blockIdx.x, ct = blockIdx.y;
  const int n0g = rt * 64;
  const int g = ct >> 1;
  const int dd0 = ct * 48;
  const float* src = (g < 2) ? h : df;
  const int cb = (g & 1) * CG;
  const int ty = tid >> 4, tx = tid & 15;
  float acc[4][3] = {};
  for (int k0 = 0; k0 < CG; k0 += 48) {
    __syncthreads();
#pragma unroll
    for (int p = 0; p < 3; ++p) {
      int e = tid + p * 256;
      int r = e / 12, c4 = (e % 12) * 4;
      *(float4*)&Gs[r][c4] = *(const float4*)&src[(size_t)(n0g + r) * CH + cb + k0 + c4];
    }
    for (int e = tid; e < 2304; e += 256) {
      int dd = e / 48, kk = e % 48;
      Ws[dd][kk] = wg[(size_t)(dd0 + dd) * CG + k0 + kk];
    }
    __syncthreads();
#pragma unroll
    for (int kq = 0; kq < 12; ++kq) {
      float4 av[4], bv[3];
#pragma unroll
      for (int i = 0; i < 4; ++i) av[i] = *(const float4*)&Gs[ty*4 + i][kq*4];
#pragma unroll
      for (int j = 0; j < 3; ++j) bv[j] = *(const float4*)&Ws[tx*3 + j][kq*4];
#pragma unroll
      for (int i = 0; i < 4; ++i)
#pragma unroll
        for (int j = 0; j < 3; ++j)
          acc[i][j] += av[i].x*bv[j].x + av[i].y*bv[j].y + av[i].z*bv[j].z + av[i].w*bv[j].w;
    }
  }
#pragma unroll
  for (int i = 0; i < 4; ++i) {
    int row = n0g + ty*4 + i;
#pragma unroll
    for (int j = 0; j < 3; ++j) {
      int oc = dd0 + tx*3 + j;
      float v = acc[i][j] + bg[oc];
      y[(size_t)row * C2 + oc] = f2bf(gelu_exact(v));
    }
  }
}

// ---------------- K5: fc2 + BN2 + residual (bf16 y input) ----------------
__global__ __launch_bounds__(256) void fc2_kernel(
    const unsigned short* __restrict__ yv, const float* __restrict__ w2,
    const float* __restrict__ b2, const float* __restrict__ x, float* __restrict__ out)
{
  __shared__ float As[64*68];
  __shared__ float Bs[64*68];
  __shared__ float Os[64*68];
  const int tid = threadIdx.x;
  const int rt = blockIdx.x, dt = blockIdx.y;
  const int n0g = rt * 64;
  const int b = n0g / NPTS;
  const int nloc0 = n0g - b * NPTS;
  const int d0 = dt * 64;
  const int ty = tid >> 4, tx = tid & 15;
  float acc[4][4] = {};
  for (int k0 = 0; k0 < C2; k0 += 64) {
    if (k0) __syncthreads();
#pragma unroll
    for (int p = 0; p < 2; ++p) {
      int e = p * 256 + tid;
      int r = e >> 3, k8 = (e & 7) * 8;
      uint4 v = *(const uint4*)&yv[(size_t)(n0g + r) * C2 + k0 + k8];
      const unsigned short* u = (const unsigned short*)&v;
#pragma unroll
      for (int j = 0; j < 8; ++j) As[r*68 + k8 + j] = bf2f(u[j]);
    }
#pragma unroll
    for (int p = 0; p < 4; ++p) {
      int e = p * 256 + tid;
      int dd = e >> 4, k4 = (e & 15) << 2;
      *(float4*)&Bs[dd*68 + k4] = *(const float4*)&w2[(size_t)(d0 + dd) * C2 + k0 + k4];
    }
    __syncthreads();
#pragma unroll
    for (int kq = 0; kq < 16; ++kq) {
      float4 av[4], bv[4];
#pragma unroll
      for (int i = 0; i < 4; ++i) av[i] = *(const float4*)&As[(ty*4+i)*68 + kq*4];
#pragma unroll
      for (int j = 0; j < 4; ++j) bv[j] = *(const float4*)&Bs[(tx*4+j)*68 + kq*4];
#pragma unroll
      for (int i = 0; i < 4; ++i)
#pragma unroll
        for (int j = 0; j < 4; ++j)
          acc[i][j] += av[i].x*bv[j].x + av[i].y*bv[j].y + av[i].z*bv[j].z + av[i].w*bv[j].w;
    }
  }
  __syncthreads();
#pragma unroll
  for (int i = 0; i < 4; ++i)
#pragma unroll
    for (int j = 0; j < 4; ++j)
      Os[(tx*4 + j)*68 + ty*4 + i] = acc[i][j];
  __syncthreads();
#pragma unroll
  for (int p = 0; p < 4; ++p) {
    int cl = (tid >> 4) + p * 16;
    int n4 = (tid & 15) << 2;
    float4 v = *(const float4*)&Os[cl*68 + n4];
    size_t gi = ((size_t)b * CH + d0 + cl) * NPTS + nloc0 + n4;
    float bb = b2[d0 + cl];
    float4 xr = *(const float4*)&x[gi];
    v.x += bb + xr.x; v.y += bb + xr.y; v.z += bb + xr.z; v.w += bb + xr.w;
    *(float4*)&out[gi] = v;
  }
}

extern "C" void kernel_launch(void* const* d_in, const int* in_sizes, int n_in,
                              void* d_out, int out_size, void* d_ws, size_t ws_size,
                              hipStream_t stream) {
  const float* x     = (const float*)d_in[0];
  const float* fc1_w = (const float*)d_in[1];
  const float* fc1_b = (const float*)d_in[2];
  const float* bn1_g = (const float*)d_in[3];
  const float* bn1_b = (const float*)d_in[4];
  const float* bn1_m = (const float*)d_in[5];
  const float* bn1_v = (const float*)d_in[6];
  const float* gc_w  = (const float*)d_in[7];
  const float* gc_b  = (const float*)d_in[8];
  const float* bng_g = (const float*)d_in[9];
  const float* bng_b = (const float*)d_in[10];
  const float* bng_m = (const float*)d_in[11];
  const float* bng_v = (const float*)d_in[12];
  const float* fc2_w = (const float*)d_in[13];
  const float* fc2_b = (const float*)d_in[14];
  const float* bn2_g = (const float*)d_in[15];
  const float* bn2_b = (const float*)d_in[16];
  const float* bn2_m = (const float*)d_in[17];
  const float* bn2_v = (const float*)d_in[18];

  float* ws = (float*)d_ws;
  size_t o = 0;
  float* W1 = ws + o; o += 36864;
  float* B1 = ws + o; o += 192;
  float* WG = ws + o; o += 36864;
  float* BG = ws + o; o += 384;
  float* W2 = ws + o; o += 73728;
  float* B2 = ws + o; o += 192;
  float* FT = ws + o; o += 64;
  float* H  = ws + o; o += (size_t)25088 * 192;     // 4,816,896 f32
  float* SQ = ws + o; o += 25088;
  int*   NN = (int*)(ws + o); o += 25088 * 9;
  float* SCR = ws + o;
  unsigned short* XHI = (unsigned short*)SCR;                    // 4,816,896 u16
  unsigned short* XLO = XHI + (size_t)25088 * 192;               // 4,816,896 u16
  float* DF  = SCR;                                              // overlays XHI+XLO (exact fit)
  float* XN  = SCR + (size_t)4816896;                            // 4,816,896 f32
  unsigned short* YB = (unsigned short*)XN;                      // overlays XN (exact fit)
  unsigned* PD = (unsigned*)(XN + (size_t)4816896);              // 25088*48 u32 packed keys
  (void)ws_size; (void)in_sizes; (void)n_in; (void)out_size;

  hipLaunchKernelGGL(prep_kernel, dim3(580), dim3(256), 0, stream,
                     fc1_w, fc1_b, bn1_g, bn1_b, bn1_m, bn1_v,
                     gc_w, gc_b, bng_g, bng_b, bng_m, bng_v,
                     fc2_w, fc2_b, bn2_g, bn2_b, bn2_m, bn2_v,
                     W1, B1, WG, BG, W2, B2, FT);
  hipLaunchKernelGGL(fc1_kernel, dim3(49, 3, 8), dim3(256), 0, stream, x, W1, B1, H);
  hipLaunchKernelGGL(norm_kernel, dim3(6272), dim3(256), 0, stream, H, XN, XHI, XLO, SQ);
  hipLaunchKernelGGL(topk_kernel, dim3(49 * MSPLIT * 8), dim3(256), 0, stream, XHI, XLO, FT, PD);
  hipLaunchKernelGGL(refine_kernel, dim3(6272), dim3(256), 0, stream, PD, XN, SQ, FT, NN);
  hipLaunchKernelGGL(edge_kernel, dim3(392), dim3(256), 0, stream, H, NN, DF);
  hipLaunchKernelGGL(gc_kernel, dim3(392, 8), dim3(256), 0, stream, H, DF, WG, BG, YB);
  hipLaunchKernelGGL(fc2_kernel, dim3(392, 3), dim3(256), 0, stream, YB, W2, B2, x, (float*)d_out);
}

// Round 8
// 501.943 us; speedup vs baseline: 7.0232x; 1.3032x over previous
//
#include <hip/hip_runtime.h>
#include <math.h>

#define BATCH 8
#define CH    192
#define WW    56
#define NPTS  3136
#define C2    384
#define CG    96
#define MT    16
#define MSPLIT 4
#define LK    12
#define NCAND (MSPLIT*LK)
#define NREF  16
#define MQ    (NPTS/MSPLIT)   // 784 rows per m-quarter

typedef float f32x4 __attribute__((ext_vector_type(4)));
typedef short bf16x8 __attribute__((ext_vector_type(8)));

__device__ __forceinline__ float gelu_exact(float v) {
  return 0.5f * v * (1.0f + erff(v * 0.7071067811865475f));
}
__device__ __forceinline__ unsigned short f2bf(float f) {
  unsigned int u = __float_as_uint(f);
  u = u + 0x7fffu + ((u >> 16) & 1u);
  return (unsigned short)(u >> 16);
}
__device__ __forceinline__ float bf2f(unsigned short h) {
  return __uint_as_float(((unsigned int)h) << 16);
}
__device__ __forceinline__ void gl_lds16(const void* g, void* lds) {
  __builtin_amdgcn_global_load_lds(
      (const __attribute__((address_space(1))) unsigned int*)g,
      (__attribute__((address_space(3))) unsigned int*)lds, 16, 0, 0);
}
// order-preserving f32 -> u32 (ascending)
__device__ __forceinline__ unsigned fmono(float f) {
  unsigned u = __float_as_uint(f);
  return u ^ ((unsigned)((int)u >> 31) | 0x80000000u);
}

// ---------------- K0: fold BN into weights, w2 -> bf16 hi/lo, cos-table ----------------
__global__ void prep_kernel(
    const float* __restrict__ fc1_w, const float* __restrict__ fc1_b,
    const float* __restrict__ bn1_g, const float* __restrict__ bn1_b,
    const float* __restrict__ bn1_m, const float* __restrict__ bn1_v,
    const float* __restrict__ gc_w,  const float* __restrict__ gc_b,
    const float* __restrict__ bng_g, const float* __restrict__ bng_b,
    const float* __restrict__ bng_m, const float* __restrict__ bng_v,
    const float* __restrict__ fc2_w, const float* __restrict__ fc2_b,
    const float* __restrict__ bn2_g, const float* __restrict__ bn2_b,
    const float* __restrict__ bn2_m, const float* __restrict__ bn2_v,
    float* __restrict__ w1, float* __restrict__ b1,
    float* __restrict__ wg, float* __restrict__ bg,
    unsigned short* __restrict__ w2h, unsigned short* __restrict__ w2l,
    float* __restrict__ b2, float* __restrict__ ftab)
{
  int i = blockIdx.x * 256 + threadIdx.x;
  if (i < 36864) {
    int d = i / CH;
    float s = bn1_g[d] / sqrtf(bn1_v[d] + 1e-5f);
    w1[i] = fc1_w[i] * s;
  } else if (i < 37056) {
    int d = i - 36864;
    float s = bn1_g[d] / sqrtf(bn1_v[d] + 1e-5f);
    b1[d] = (fc1_b[d] - bn1_m[d]) * s + bn1_b[d];
  } else if (i < 73920) {
    int j = i - 37056;
    int o = j / CG;
    float s = bng_g[o] / sqrtf(bng_v[o] + 1e-5f);
    wg[j] = gc_w[j] * s;
  } else if (i < 74304) {
    int o = i - 73920;
    float s = bng_g[o] / sqrtf(bng_v[o] + 1e-5f);
    bg[o] = (gc_b[o] - bng_m[o]) * s + bng_b[o];
  } else if (i < 148032) {
    int j = i - 74304;
    int d = j / C2;
    float s = bn2_g[d] / sqrtf(bn2_v[d] + 1e-5f);
    float v = fc2_w[j] * s;
    unsigned short hi = f2bf(v);
    w2h[j] = hi;
    w2l[j] = f2bf(v - bf2f(hi));
  } else if (i < 148224) {
    int d = i - 148032;
    float s = bn2_g[d] / sqrtf(bn2_v[d] + 1e-5f);
    b2[d] = (fc2_b[d] - bn2_m[d]) * s + bn2_b[d];
  } else if (i < 148280) {
    int delta = i - 148224;
    float s = 0.f;
    for (int t = 0; t < 48; ++t) {
      float omega = powf(10000.f, -(float)t / 48.f);
      s += cosf((float)delta * omega);
    }
    ftab[delta] = s * (-2.0f / (float)CH);   // pre-scaled: rel = ft[dy]+ft[dx]
  }
}

// ---------------- K1: h = BN1(fc1(x^T)) ; h layout [b][n][c] ----------------
__global__ __launch_bounds__(256) void fc1_kernel(
    const float* __restrict__ x, const float* __restrict__ w1,
    const float* __restrict__ b1, float* __restrict__ h)
{
  __shared__ float As[64*68];
  __shared__ float Bs[64*68];
  const int tid = threadIdx.x;
  const int ntile = blockIdx.x, dt = blockIdx.y, b = blockIdx.z;
  const int n0 = ntile * 64, d0 = dt * 64;
  const int ty = tid >> 4, tx = tid & 15;
  const float* xb = x + (size_t)b * CH * NPTS;
  float acc[4][4] = {};
  for (int k0 = 0; k0 < CH; k0 += 64) {
    if (k0) __syncthreads();
#pragma unroll
    for (int p = 0; p < 16; ++p) {
      int e = p * 256 + tid;
      int kk = e >> 6, r = e & 63;
      As[r*68 + kk] = xb[(size_t)(k0 + kk) * NPTS + n0 + r];
    }
#pragma unroll
    for (int p = 0; p < 4; ++p) {
      int e = p * 256 + tid;
      int dd = e >> 4, k4 = (e & 15) << 2;
      *(float4*)&Bs[dd*68 + k4] = *(const float4*)&w1[(size_t)(d0 + dd) * CH + k0 + k4];
    }
    __syncthreads();
#pragma unroll
    for (int kq = 0; kq < 16; ++kq) {
      float4 av[4], bv[4];
#pragma unroll
      for (int i = 0; i < 4; ++i) av[i] = *(const float4*)&As[(ty*4+i)*68 + kq*4];
#pragma unroll
      for (int j = 0; j < 4; ++j) bv[j] = *(const float4*)&Bs[(tx*4+j)*68 + kq*4];
#pragma unroll
      for (int i = 0; i < 4; ++i)
#pragma unroll
        for (int j = 0; j < 4; ++j)
          acc[i][j] += av[i].x*bv[j].x + av[i].y*bv[j].y + av[i].z*bv[j].z + av[i].w*bv[j].w;
    }
  }
#pragma unroll
  for (int i = 0; i < 4; ++i) {
    int n = n0 + ty*4 + i;
    float4 v;
    v.x = acc[i][0] + b1[d0 + tx*4 + 0];
    v.y = acc[i][1] + b1[d0 + tx*4 + 1];
    v.z = acc[i][2] + b1[d0 + tx*4 + 2];
    v.w = acc[i][3] + b1[d0 + tx*4 + 3];
    *(float4*)&h[((size_t)b * NPTS + n) * CH + d0 + tx*4] = v;
  }
}

// ---------------- K2: xn (f32 + bf16 hi/lo split) + sq ----------------
__global__ __launch_bounds__(256) void norm_kernel(
    const float* __restrict__ h, float* __restrict__ xnf,
    unsigned short* __restrict__ xhi, unsigned short* __restrict__ xlo,
    float* __restrict__ sqv)
{
  const int lane = threadIdx.x & 63;
  const int row = blockIdx.x * 4 + (threadIdx.x >> 6);
  const float* hr = h + (size_t)row * CH;
  float v0 = hr[lane], v1 = hr[lane + 64], v2 = hr[lane + 128];
  float s = v0*v0 + v1*v1 + v2*v2;
#pragma unroll
  for (int o = 32; o > 0; o >>= 1) s += __shfl_xor(s, o);
  float inv = 1.0f / fmaxf(sqrtf(s), 1e-12f);
  float x0 = v0 * inv, x1 = v1 * inv, x2 = v2 * inv;
  size_t base = (size_t)row * CH;
  xnf[base + lane      ] = x0;
  xnf[base + lane + 64 ] = x1;
  xnf[base + lane + 128] = x2;
  unsigned short h0 = f2bf(x0), h1 = f2bf(x1), h2 = f2bf(x2);
  xhi[base + lane      ] = h0;
  xhi[base + lane + 64 ] = h1;
  xhi[base + lane + 128] = h2;
  xlo[base + lane      ] = f2bf(x0 - bf2f(h0));
  xlo[base + lane + 64 ] = f2bf(x1 - bf2f(h1));
  xlo[base + lane + 128] = f2bf(x2 - bf2f(h2));
  if (lane == 0) sqv[row] = s * inv * inv;
}

// ---------------- K3: MFMA coarse dist, per-lane packed-key top-12 ----------------
__global__ __launch_bounds__(256, 4) void topk_kernel(
    const unsigned short* __restrict__ xhi, const unsigned short* __restrict__ xlo,
    const float* __restrict__ fts_g,
    unsigned* __restrict__ pd)
{
  __shared__ __align__(16) char LDSbuf[2 * 12288];   // [buf][hi 6144 | lo 6144]
  __shared__ float ft[64];

  const int tid  = threadIdx.x;
  const int lane = tid & 63;
  const int w    = tid >> 6;
  const int bid  = blockIdx.x;
  const int b    = bid & 7;            // XCD-aligned (round-robin assumption)
  const int r_   = bid >> 3;
  const int ms   = r_ / 49;
  const int nt   = r_ % 49;
  const int n0 = nt * 64;
  const size_t rowbase = (size_t)b * NPTS;

  if (tid < 64) ft[tid] = (tid < 56) ? fts_g[tid] : 0.0f;

  const int ar = lane & 15;
  const int hi = lane >> 4;
  const int ak = hi * 8;

  const int n_b = n0 + w * 16 + ar;
  bf16x8 bhi[6], blo[6];
  {
    const unsigned short* pbh = xhi + (rowbase + n_b) * CH + ak;
    const unsigned short* pbl = xlo + (rowbase + n_b) * CH + ak;
#pragma unroll
    for (int c = 0; c < 6; ++c) {
      bhi[c] = *(const bf16x8*)(pbh + c * 32);
      blo[c] = *(const bf16x8*)(pbl + c * 32);
    }
  }
  const int yn_l = n_b / WW, xn_l = n_b % WW;

  unsigned ld[LK];
#pragma unroll
  for (int k = 0; k < LK; ++k) ld[k] = 0xFFFFFFFFu;

  int srcb[3];
#pragma unroll
  for (int j = 0; j < 3; ++j) {
    int L = (w & 1) * 3072 + j * 1024 + lane * 16;
    int r = L / 384, off = L % 384;
    srcb[j] = r * 384 + (off ^ ((r & 7) << 4));
  }
  const int ldsb = (w >= 2 ? 6144 : 0) + (w & 1) * 3072;

  const int mbase = ms * MQ;
  const char* gb = (w < 2 ? (const char*)xhi : (const char*)xlo)
                   + (rowbase + mbase) * (CH * 2);

#define STAGE(BUF) do {                                                     \
  _Pragma("unroll")                                                         \
  for (int j = 0; j < 3; ++j)                                               \
    gl_lds16(gb + srcb[j], LDSbuf + (BUF) * 12288 + ldsb + j * 1024);       \
} while (0)

  STAGE(0);
  gb += 6144;

  int ym0 = ms * 14, xm0 = 0;

  for (int tt = 0; tt < 49; ++tt) {
    __syncthreads();
    if (tt + 1 < 49) { STAGE((tt + 1) & 1); gb += 6144; }

    const int bufb = (tt & 1) * 12288;
    const int swz = (ar & 7) << 4;
    f32x4 a_hh = {}, a_hl = {}, a_lh = {};
#pragma unroll
    for (int c = 0; c < 6; ++c) {
      int off = bufb + ar * 384 + ((c * 64 + hi * 16) ^ swz);
      bf16x8 ah = *(const bf16x8*)(LDSbuf + off);
      bf16x8 al = *(const bf16x8*)(LDSbuf + off + 6144);
      a_hh = __builtin_amdgcn_mfma_f32_16x16x32_bf16(ah, bhi[c], a_hh, 0, 0, 0);
      a_hl = __builtin_amdgcn_mfma_f32_16x16x32_bf16(ah, blo[c], a_hl, 0, 0, 0);
      a_lh = __builtin_amdgcn_mfma_f32_16x16x32_bf16(al, bhi[c], a_lh, 0, 0, 0);
    }
    f32x4 s4;
#pragma unroll
    for (int i = 0; i < 4; ++i) s4[i] = a_hh[i] + (a_hl[i] + a_lh[i]);

    const float fdy0 = ft[abs(yn_l - ym0)];
    const float fdy1 = ft[abs(yn_l - ym0 - 1)];
    const int locb = tt * MT + hi * 4;
#pragma unroll
    for (int i = 0; i < 4; ++i) {
      int xm = xm0 + hi * 4 + i;
      const bool wrap = (xm >= WW);
      if (wrap) xm -= WW;
      int dx = xn_l - xm; dx = dx < 0 ? -dx : dx;
      float d_ = (wrap ? fdy1 : fdy0) + ft[dx] - 2.0f * s4[i];
      unsigned key = (fmono(d_) & 0xFFFFFC00u) | (unsigned)(locb + i);
      if (key < ld[LK-1]) {
        unsigned cd = key;
#pragma unroll
        for (int s = 0; s < LK; ++s) {
          unsigned mn = ld[s] < cd ? ld[s] : cd;
          unsigned mx = ld[s] < cd ? cd : ld[s];
          ld[s] = mn; cd = mx;
        }
      }
    }
    xm0 += MT;
    if (xm0 >= WW) { xm0 -= WW; ym0 += 1; }
  }

  __syncthreads();
  unsigned* Md = (unsigned*)LDSbuf;
#pragma unroll
  for (int k = 0; k < LK; ++k) Md[tid * LK + k] = ld[k];
  __syncthreads();
  if (tid < 64) {
    const int wv = tid >> 4, arr = tid & 15;
    const int n = n0 + tid;
    int lb[4];
#pragma unroll
    for (int hq = 0; hq < 4; ++hq) lb[hq] = (wv * 64 + hq * 16 + arr) * LK;
    int p0 = 0, p1 = 0, p2 = 0, p3 = 0;
    unsigned* od = pd + ((rowbase + n) * MSPLIT + ms) * LK;
    for (int k = 0; k < LK; ++k) {
      unsigned bk = Md[lb[0] + p0]; int bq = 0;
      unsigned v1 = Md[lb[1] + p1];
      if (v1 < bk) { bk = v1; bq = 1; }
      unsigned v2 = Md[lb[2] + p2];
      if (v2 < bk) { bk = v2; bq = 2; }
      unsigned v3 = Md[lb[3] + p3];
      if (v3 < bk) { bk = v3; bq = 3; }
      if (bq == 0) { if (p0 < LK-1) ++p0; else Md[lb[0]+p0] = 0xFFFFFFFFu; }
      else if (bq == 1) { if (p1 < LK-1) ++p1; else Md[lb[1]+p1] = 0xFFFFFFFFu; }
      else if (bq == 2) { if (p2 < LK-1) ++p2; else Md[lb[2]+p2] = 0xFFFFFFFFu; }
      else              { if (p3 < LK-1) ++p3; else Md[lb[3]+p3] = 0xFFFFFFFFu; }
      od[k] = bk;
    }
  }
#undef STAGE
}

// ---------------- K3b: pool 48 packed coarse keys -> exact f32 refine -> top-9 ----------------
__global__ __launch_bounds__(256) void refine_kernel(
    const unsigned* __restrict__ pd,
    const float* __restrict__ xn, const float* __restrict__ sqv,
    const float* __restrict__ fts_g, int* __restrict__ nn)
{
  __shared__ unsigned allk[4][NCAND];
  __shared__ int      ci_s[4][NREF];
  __shared__ float ft[56];
  const int tid = threadIdx.x;
  const int w = tid >> 6, lane = tid & 63;
  if (tid < 56) ft[tid] = fts_g[tid];
  const int row = blockIdx.x * 4 + w;
  const int b = row / NPTS;
  const int n_loc = row - b * NPTS;

  if (lane < NCAND) allk[w][lane] = pd[(size_t)row * NCAND + lane];
  __syncthreads();
  if (lane < NCAND) {
    unsigned k0 = allk[w][lane];
    int rank = 0;
    for (int j = 0; j < NCAND; ++j) {
      unsigned kj = allk[w][j];
      rank += (kj < k0 || (kj == k0 && j < lane)) ? 1 : 0;
    }
    if (rank < NREF) ci_s[w][rank] = (lane / LK) * MQ + (int)(k0 & 1023u);
  }
  __syncthreads();

  const float* xrow = xn + (size_t)row * CH;
  float a0 = xrow[lane], a1 = xrow[lane + 64], a2 = xrow[lane + 128];
  const int yn_ = n_loc / WW, xq_ = n_loc % WW;
  const size_t xbase = (size_t)b * NPTS * CH;
  float myd = INFINITY; int myi = 0x7fffffff;
#pragma unroll 4
  for (int c = 0; c < NREF; ++c) {
    int m = ci_s[w][c];
    const float* xm = xn + xbase + (size_t)m * CH;
    float s = a0 * xm[lane] + a1 * xm[lane + 64] + a2 * xm[lane + 128];
#pragma unroll
    for (int o = 32; o > 0; o >>= 1) s += __shfl_xor(s, o);
    if (lane == c) {
      int ym = m / WW, xm_ = m % WW;
      int dy = yn_ - ym; dy = dy < 0 ? -dy : dy;
      int dx = xq_ - xm_; dx = dx < 0 ? -dx : dx;
      myd = sqv[(size_t)b * NPTS + m] - 2.0f * s + (ft[dy] + ft[dx]);
      myi = m;
    }
  }
  if (lane < NREF) {
    int rank = 0;
    for (int j = 0; j < NREF; ++j) {
      float dj = __shfl(myd, j); int ij = __shfl(myi, j);
      rank += (dj < myd || (dj == myd && ij < myi)) ? 1 : 0;
    }
    if (rank < 9) nn[(size_t)row * 9 + rank] = myi;
  }
}

// ---------------- K3c: edge features d = max_j(x_j) - h, once ----------------
__global__ __launch_bounds__(256) void edge_kernel(
    const float* __restrict__ h, const int* __restrict__ nn,
    float* __restrict__ df)
{
  __shared__ int nns[576];
  const int n0g = blockIdx.x * 64;
  const int b = n0g / NPTS;
  const size_t rowbase = (size_t)b * NPTS;
  const int tid = threadIdx.x;
  for (int e = tid; e < 576; e += 256)
    nns[e] = nn[(size_t)(n0g + e / 9) * 9 + (e % 9)];
  __syncthreads();
#pragma unroll
  for (int p = 0; p < 12; ++p) {
    int e = tid + 256 * p;
    int r = e / 48, c4 = (e % 48) * 4;
    float4 hv = *(const float4*)&h[(size_t)(n0g + r) * CH + c4];
    float4 mx = make_float4(-INFINITY, -INFINITY, -INFINITY, -INFINITY);
#pragma unroll
    for (int k = 0; k < 9; ++k) {
      float4 nv = *(const float4*)&h[(rowbase + nns[r*9 + k]) * CH + c4];
      mx.x = fmaxf(mx.x, nv.x); mx.y = fmaxf(mx.y, nv.y);
      mx.z = fmaxf(mx.z, nv.z); mx.w = fmaxf(mx.w, nv.w);
    }
    float4 ov;
    ov.x = mx.x - hv.x; ov.y = mx.y - hv.y; ov.z = mx.z - hv.z; ov.w = mx.w - hv.w;
    *(float4*)&df[(size_t)(n0g + r) * CH + c4] = ov;
  }
}

// ---------------- K4: grouped GEMM + GELU (no gathers), y in bf16 ----------------
__global__ __launch_bounds__(256) void gc_kernel(
    const float* __restrict__ h, const float* __restrict__ df,
    const float* __restrict__ wg, const float* __restrict__ bg,
    unsigned short* __restrict__ y)
{
  __shared__ float Gs[64][52];
  __shared__ float Ws[48][52];
  const int tid = threadIdx.x;
  const int rt = blockIdx.x, ct = blockIdx.y;
  const int n0g = rt * 64;
  const int g = ct >> 1;
  const int dd0 = ct * 48;
  const float* src = (g < 2) ? h : df;
  const int cb = (g & 1) * CG;
  const int ty = tid >> 4, tx = tid & 15;
  float acc[4][3] = {};
  for (int k0 = 0; k0 < CG; k0 += 48) {
    __syncthreads();
#pragma unroll
    for (int p = 0; p < 3; ++p) {
      int e = tid + p * 256;
      int r = e / 12, c4 = (e % 12) * 4;
      *(float4*)&Gs[r][c4] = *(const float4*)&src[(size_t)(n0g + r) * CH + cb + k0 + c4];
    }
    for (int e = tid; e < 2304; e += 256) {
      int dd = e / 48, kk = e % 48;
      Ws[dd][kk] = wg[(size_t)(dd0 + dd) * CG + k0 + kk];
    }
    __syncthreads();
#pragma unroll
    for (int kq = 0; kq < 12; ++kq) {
      float4 av[4], bv[3];
#pragma unroll
      for (int i = 0; i < 4; ++i) av[i] = *(const float4*)&Gs[ty*4 + i][kq*4];
#pragma unroll
      for (int j = 0; j < 3; ++j) bv[j] = *(const float4*)&Ws[tx*3 + j][kq*4];
#pragma unroll
      for (int i = 0; i < 4; ++i)
#pragma unroll
        for (int j = 0; j < 3; ++j)
          acc[i][j] += av[i].x*bv[j].x + av[i].y*bv[j].y + av[i].z*bv[j].z + av[i].w*bv[j].w;
    }
  }
#pragma unroll
  for (int i = 0; i < 4; ++i) {
    int row = n0g + ty*4 + i;
#pragma unroll
    for (int j = 0; j < 3; ++j) {
      int oc = dd0 + tx*3 + j;
      float v = acc[i][j] + bg[oc];
      y[(size_t)row * C2 + oc] = f2bf(gelu_exact(v));
    }
  }
}

// ---------------- K5: fc2 via MFMA (y exact bf16; w2 hi/lo split) + BN2 + residual ----------------
// grid (392, 3): 64-n tile x 64-d group. A = w2 d-rows (LDS, XOR-swizzled via
// inverse-swizzled gl_lds source), B = y n-rows (registers, exact bf16).
// C: row=d, col=n -> coalesced transposed store with bias+residual fused.
__global__ __launch_bounds__(256, 4) void fc2_kernel(
    const unsigned short* __restrict__ yv,
    const unsigned short* __restrict__ w2h, const unsigned short* __restrict__ w2l,
    const float* __restrict__ b2, const float* __restrict__ x, float* __restrict__ out)
{
  __shared__ __align__(16) char Wb[2 * 12288];   // [hi 12288 | lo 12288] for 16-d subtile
  const int tid = threadIdx.x;
  const int lane = tid & 63;
  const int w = tid >> 6;
  const int rt = blockIdx.x, dg = blockIdx.y;
  const int n0g = rt * 64;
  const int b = n0g / NPTS;
  const int nloc0 = n0g - b * NPTS;
  const int cn = lane & 15;            // n-within-wave (C col)
  const int kk0 = (lane >> 4) * 8;     // k-element base

  // B-operand: y row, 12 k-chunks (exact bf16 -> no split needed)
  bf16x8 yb[12];
  {
    const unsigned short* yp = yv + (size_t)(n0g + w * 16 + cn) * C2 + kk0;
#pragma unroll
    for (int c = 0; c < 12; ++c) yb[c] = *(const bf16x8*)(yp + c * 32);
  }

  // stage offsets: LDS linear L = (w*3+j)*1024 + lane*16 ; src = r*768 + (off^swz(r))
  int srcb[3], dstb[3];
#pragma unroll
  for (int j = 0; j < 3; ++j) {
    int L = (w * 3 + j) * 1024 + lane * 16;
    int r = L / 768, off = L % 768;
    srcb[j] = r * 768 + (off ^ ((r & 7) << 4));
    dstb[j] = (w * 3 + j) * 1024;
  }

  const char* gh = (const char*)w2h + (size_t)dg * 64 * 768;
  const char* gl = (const char*)w2l + (size_t)dg * 64 * 768;
  const int rr = cn;                   // A-row within subtile
  const int swz = (rr & 7) << 4;
  const int nsp = nloc0 + w * 16 + cn;

  for (int ds = 0; ds < 4; ++ds) {
    __syncthreads();                   // prior subtile LDS reads done
#pragma unroll
    for (int j = 0; j < 3; ++j) {
      gl_lds16(gh + ds * 12288 + srcb[j], Wb + dstb[j]);
      gl_lds16(gl + ds * 12288 + srcb[j], Wb + 12288 + dstb[j]);
    }
    __syncthreads();                   // vmcnt drained -> subtile staged

    f32x4 acc_h = {}, acc_l = {};
#pragma unroll
    for (int c = 0; c < 12; ++c) {
      int off = rr * 768 + ((c * 64 + (lane >> 4) * 16) ^ swz);
      bf16x8 ah = *(const bf16x8*)(Wb + off);
      bf16x8 al = *(const bf16x8*)(Wb + 12288 + off);
      acc_h = __builtin_amdgcn_mfma_f32_16x16x32_bf16(ah, yb[c], acc_h, 0, 0, 0);
      acc_l = __builtin_amdgcn_mfma_f32_16x16x32_bf16(al, yb[c], acc_l, 0, 0, 0);
    }
    const int d0 = dg * 64 + ds * 16;
#pragma unroll
    for (int i = 0; i < 4; ++i) {
      int d = d0 + (lane >> 4) * 4 + i;
      size_t gi = ((size_t)b * CH + d) * NPTS + nsp;
      out[gi] = acc_h[i] + acc_l[i] + b2[d] + x[gi];
    }
  }
}

extern "C" void kernel_launch(void* const* d_in, const int* in_sizes, int n_in,
                              void* d_out, int out_size, void* d_ws, size_t ws_size,
                              hipStream_t stream) {
  const float* x     = (const float*)d_in[0];
  const float* fc1_w = (const float*)d_in[1];
  const float* fc1_b = (const float*)d_in[2];
  const float* bn1_g = (const float*)d_in[3];
  const float* bn1_b = (const float*)d_in[4];
  const float* bn1_m = (const float*)d_in[5];
  const float* bn1_v = (const float*)d_in[6];
  const float* gc_w  = (const float*)d_in[7];
  const float* gc_b  = (const float*)d_in[8];
  const float* bng_g = (const float*)d_in[9];
  const float* bng_b = (const float*)d_in[10];
  const float* bng_m = (const float*)d_in[11];
  const float* bng_v = (const float*)d_in[12];
  const float* fc2_w = (const float*)d_in[13];
  const float* fc2_b = (const float*)d_in[14];
  const float* bn2_g = (const float*)d_in[15];
  const float* bn2_b = (const float*)d_in[16];
  const float* bn2_m = (const float*)d_in[17];
  const float* bn2_v = (const float*)d_in[18];

  float* ws = (float*)d_ws;
  size_t o = 0;
  float* W1 = ws + o; o += 36864;
  float* B1 = ws + o; o += 192;
  float* WG = ws + o; o += 36864;
  float* BG = ws + o; o += 384;
  unsigned short* W2H = (unsigned short*)(ws + o); o += 36864;   // 73728 bf16
  unsigned short* W2L = (unsigned short*)(ws + o); o += 36864;   // 73728 bf16
  float* B2 = ws + o; o += 192;
  float* FT = ws + o; o += 64;
  float* H  = ws + o; o += (size_t)25088 * 192;     // 4,816,896 f32
  float* SQ = ws + o; o += 25088;
  int*   NN = (int*)(ws + o); o += 25088 * 9;
  float* SCR = ws + o;
  unsigned short* XHI = (unsigned short*)SCR;                    // 4,816,896 u16
  unsigned short* XLO = XHI + (size_t)25088 * 192;               // 4,816,896 u16
  float* DF  = SCR;                                              // overlays XHI+XLO (exact fit)
  float* XN  = SCR + (size_t)4816896;                            // 4,816,896 f32
  unsigned short* YB = (unsigned short*)XN;                      // overlays XN (exact fit)
  unsigned* PD = (unsigned*)(XN + (size_t)4816896);              // 25088*48 u32 packed keys
  (void)ws_size; (void)in_sizes; (void)n_in; (void)out_size;

  hipLaunchKernelGGL(prep_kernel, dim3(580), dim3(256), 0, stream,
                     fc1_w, fc1_b, bn1_g, bn1_b, bn1_m, bn1_v,
                     gc_w, gc_b, bng_g, bng_b, bng_m, bng_v,
                     fc2_w, fc2_b, bn2_g, bn2_b, bn2_m, bn2_v,
                     W1, B1, WG, BG, W2H, W2L, B2, FT);
  hipLaunchKernelGGL(fc1_kernel, dim3(49, 3, 8), dim3(256), 0, stream, x, W1, B1, H);
  hipLaunchKernelGGL(norm_kernel, dim3(6272), dim3(256), 0, stream, H, XN, XHI, XLO, SQ);
  hipLaunchKernelGGL(topk_kernel, dim3(49 * MSPLIT * 8), dim3(256), 0, stream, XHI, XLO, FT, PD);
  hipLaunchKernelGGL(refine_kernel, dim3(6272), dim3(256), 0, stream, PD, XN, SQ, FT, NN);
  hipLaunchKernelGGL(edge_kernel, dim3(392), dim3(256), 0, stream, H, NN, DF);
  hipLaunchKernelGGL(gc_kernel, dim3(392, 8), dim3(256), 0, stream, H, DF, WG, BG, YB);
  hipLaunchKernelGGL(fc2_kernel, dim3(392, 3), dim3(256), 0, stream, YB, W2H, W2L, B2, x, (float*)d_out);
}